// Round 7
// baseline (358.891 us; speedup 1.0000x reference)
//
#include <hip/hip_runtime.h>
#include <hip/hip_bf16.h>

typedef __hip_bfloat16 bf16;
typedef __attribute__((ext_vector_type(8))) short bf8_t;  // 8 bf16 (4 VGPR)
typedef __attribute__((ext_vector_type(4))) float f4_t;

__device__ __forceinline__ float b2f(bf16 x) { return __bfloat162float(x); }

__device__ __forceinline__ float ldany(const void* p, size_t i, int isbf) {
    return isbf ? b2f(((const bf16*)p)[i]) : ((const float*)p)[i];
}

// fp32 -> bf16 (RTN-even), bit pattern as short
__device__ __forceinline__ short f2b(float f) {
    unsigned u = __builtin_bit_cast(unsigned, f);
    u += 0x7fffu + ((u >> 16) & 1u);
    return (short)(u >> 16);
}

__device__ __forceinline__ void gload16(const short* g, short* l) {
    __builtin_amdgcn_global_load_lds(
        (const __attribute__((address_space(1))) void*)g,
        (__attribute__((address_space(3))) void*)l, 16, 0, 0);
}

__device__ __forceinline__ void fma4(float4& a, const float4& x,
                                     const float4& y) {
    a.x += x.x * y.x; a.y += x.y * y.y;
    a.z += x.z * y.z; a.w += x.w * y.w;
}
__device__ __forceinline__ void fma4s(float4& a, const float4& x, float s) {
    a.x += x.x * s; a.y += x.y * s; a.z += x.z * s; a.w += x.w * s;
}
__device__ __forceinline__ float sum4(const float4& a) {
    return (a.x + a.y) + (a.z + a.w);
}
// component select; folds to static with unrolled constant c
__device__ __forceinline__ float getc(const float4& v, int c) {
    return c == 0 ? v.x : c == 1 ? v.y : c == 2 ? v.z : v.w;
}

// ---------------------------------------------------------------- prep
// detect (per-block local) + to-bf16 (vectorized) + weight transpose.
struct WT15 {
    const void* src[15];
};

__global__ __launch_bounds__(256) void k_prep(
    const void* __restrict__ dec, const void* __restrict__ enc,
    const void* __restrict__ p, short* __restrict__ dec_bf,
    short* __restrict__ enc_bf, short* __restrict__ p_bf, WT15 w,
    short* __restrict__ wt, short* __restrict__ ff1t,
    short* __restrict__ ff2t, int* __restrict__ flagp) {
    __shared__ float T[32][33];
    __shared__ int cntS;
    if (threadIdx.x == 0) cntS = 0;
    __syncthreads();
    {
        float f = b2f(((const bf16*)dec)[threadIdx.x]);  // first 256 bf16
        float a = fabsf(f);
        int bad = (!(a < 1e10f) || (a != 0.f && a < 1e-20f)) ? 1 : 0;
#pragma unroll
        for (int off = 32; off >= 1; off >>= 1)
            bad += __shfl_xor(bad, off, 64);
        if ((threadIdx.x & 63) == 0) atomicAdd(&cntS, bad);
    }
    __syncthreads();
    int isbf = (cntS >= 3) ? 0 : 1;
    if (blockIdx.x == 0 && threadIdx.x == 0) *flagp = isbf;
    int id = blockIdx.x;
    if (id < 2080) {  // to-bf16: 2129920 elements, 4/thread vectorized
        size_t i4 = ((size_t)id * 256 + threadIdx.x) * 4;
        const void* src;
        short* dst;
        size_t idx;
        if (i4 < 1048576) { src = dec; dst = dec_bf; idx = i4; }
        else if (i4 < 2097152) { src = enc; dst = enc_bf; idx = i4 - 1048576; }
        else { src = p; dst = p_bf; idx = i4 - 2097152; }
        if (isbf) {
            *(short4*)&dst[idx] =
                ((const short4*)((const short*)src))[idx >> 2];
        } else {
            float4 f = ((const float4*)((const float*)src))[idx >> 2];
            short4 o;
            o.x = f2b(f.x); o.y = f2b(f.y); o.z = f2b(f.z); o.w = f2b(f.w);
            *(short4*)&dst[idx] = o;
        }
        return;
    }
    id -= 2080;
    const void* src;
    short* d;
    int K, N, bx, by;
    if (id < 3328) {              // 13 square 512x512 slabs
        int slab = id >> 8, rem = id & 255;
        src = w.src[slab];
        d = wt + (size_t)slab * 262144;
        K = 512; N = 512;
        bx = rem & 15; by = rem >> 4;
    } else if (id < 4352) {       // ff1
        int rem = id - 3328;
        src = w.src[13]; d = ff1t;
        K = 512; N = 2048;
        bx = rem & 63; by = rem >> 6;
    } else {                      // ff2
        int rem = id - 4352;
        src = w.src[14]; d = ff2t;
        K = 2048; N = 512;
        bx = rem & 15; by = rem >> 4;
    }
    int nb = bx * 32, kb = by * 32;
    int col = threadIdx.x & 31, row0 = threadIdx.x >> 5;
#pragma unroll
    for (int i = 0; i < 4; i++) {
        int r = row0 + i * 8;
        T[r][col] = ldany(src, (size_t)(kb + r) * N + nb + col, isbf);
    }
    __syncthreads();
#pragma unroll
    for (int i = 0; i < 4; i++) {
        int r = row0 + i * 8;
        d[(size_t)(nb + r) * K + kb + col] = f2b(T[col][r]);
    }
}

// ---------------------------------------------------------------- MFMA GEMM
// R4 structure (best measured): 2-buffer LDS, global_load_lds(16B),
// STAGE(next) -> MFMA(cur) -> vmcnt(0) -> barrier.
struct GJob {
    const short* A;
    const short* W[4];
    const void* Bias[4];
    float scale[4];
    float* Out[4];
    short* OutBf[4];
    const float* Res;
    const void* ResAny;
    int Nper, K, relu;
    int gx, nblk, blk0;
};
struct GTail {
    int blk0;
    const float* partC;
    const float* ml;
    const void* p_in;
    const void* gv;
    const void* bv;
    short* yp_bf;
    void* outany;
    unsigned long long ooff;
};
struct GJobs {
    GJob j[3];
    GTail tail;
    int nj;
};

__device__ void red_ln_dev(const GTail& T, int row, int isbf, float* red) {
    int b = row >> 5, i = row & 31;
    float v[2];
#pragma unroll
    for (int t = 0; t < 2; t++) {
        int col = (int)threadIdx.x + t * 256;
        int h = col >> 6, dd = col & 63;
        int bh = b * 8 + h;
        float M = -1e30f;
        for (int ks2 = 0; ks2 < 16; ks2++)
            M = fmaxf(M, T.ml[((size_t)bh * 16 + ks2) * 64 + i * 2]);
        float L = 0.f, acc = 0.f;
        for (int ks2 = 0; ks2 < 16; ks2++) {
            float m = T.ml[((size_t)bh * 16 + ks2) * 64 + i * 2];
            float l = T.ml[((size_t)bh * 16 + ks2) * 64 + i * 2 + 1];
            float w = expf(m - M);
            L += l * w;
            acc += T.partC[((size_t)bh * 16 + ks2) * 2048 + i * 64 + dd] * w;
        }
        float raw = acc / L;
        size_t o = (size_t)(b * 32 + i) * 512 + col;
        T.yp_bf[o] = f2b(raw);
        v[t] = raw + ldany(T.p_in, o, isbf);
    }
    int wave = threadIdx.x >> 6, lane = threadIdx.x & 63;
    float sum = v[0] + v[1];
#pragma unroll
    for (int off = 32; off >= 1; off >>= 1) sum += __shfl_xor(sum, off, 64);
    if (lane == 0) red[wave] = sum;
    __syncthreads();
    float mean = (red[0] + red[1] + red[2] + red[3]) * (1.f / 512.f);
    float var = 0.f;
#pragma unroll
    for (int t = 0; t < 2; t++) {
        float dd = v[t] - mean;
        var += dd * dd;
    }
#pragma unroll
    for (int off = 32; off >= 1; off >>= 1) var += __shfl_xor(var, off, 64);
    if (lane == 0) red[wave + 4] = var;
    __syncthreads();
    var = (red[4] + red[5] + red[6] + red[7]) * (1.f / 512.f);
    float inv = rsqrtf(var + 1e-5f);
#pragma unroll
    for (int t = 0; t < 2; t++) {
        int col = (int)threadIdx.x + t * 256;
        size_t o = (size_t)((row >> 5) * 32 + (row & 31)) * 512 + col;
        float y = (v[t] - mean) * inv * ldany(T.gv, col, isbf) +
                  ldany(T.bv, col, isbf);
        if (isbf)
            ((bf16*)T.outany + T.ooff)[o] = __float2bfloat16(y);
        else
            ((float*)T.outany + T.ooff)[o] = y;
    }
}

__global__ __launch_bounds__(256, 4) void k_gemm_mfma(
    GJobs gs, const int* __restrict__ flagp) {
    __shared__ __align__(16) short As[2][64 * 64];
    __shared__ __align__(16) short Bs[2][64 * 64];
    __shared__ float redS[8];
    int isbf = *flagp;
    int id = blockIdx.x;
    if (id >= gs.tail.blk0) {
        red_ln_dev(gs.tail, id - gs.tail.blk0, isbf, redS);
        return;
    }
    int tid = threadIdx.x;
    int wave = tid >> 6, lane = tid & 63;
    int quad = lane >> 4, l16 = lane & 15;
    int ji = 0;
    if (gs.nj > 1 && id >= gs.j[1].blk0) ji = 1;
    if (gs.nj > 2 && id >= gs.j[2].blk0) ji = 2;
    const GJob& jb = gs.j[ji];
    int lid = id - jb.blk0;
    int gx = jb.gx, nblk = jb.nblk;
    int bx, by;
    if ((nblk & 7) == 0) {
        int per = nblk >> 3;
        int id2 = (lid & 7) * per + (lid >> 3);
        by = id2 / gx;
        bx = id2 - by * gx;
    } else {
        by = lid / gx;
        bx = lid - by * gx;
    }
    int K = jb.K;
    int mb = by * 64;
    int nbg = bx * 64;
    int slot = nbg / jb.Nper;
    int nb = nbg - slot * jb.Nper;
    const short* Wt = jb.W[slot];
    const short* A = jb.A;
    int wn = wave * 16;
    f4_t acc[4] = {};

    const short* Ap = A + (size_t)mb * K;
    const short* Wp = Wt + (size_t)nb * K;
    int w8 = wave * 8;
    int lr = lane >> 3;
    int lc = ((lane & 7) ^ lr) * 8;  // swizzled short offset within row
    const short* ga0 = Ap + (size_t)(w8 + lr) * K + lc;
    const short* gb0 = Wp + (size_t)(w8 + lr) * K + lc;
    short* la0 = &As[0][w8 * 64];
    short* lb0 = &Bs[0][w8 * 64];

    auto stage = [&](int buf, int k) {
        gload16(ga0 + k, la0 + buf * 4096);
        gload16(ga0 + (size_t)32 * K + k, la0 + buf * 4096 + 32 * 64);
        gload16(gb0 + k, lb0 + buf * 4096);
        gload16(gb0 + (size_t)32 * K + k, lb0 + buf * 4096 + 32 * 64);
    };

    int sw = l16 & 7;

    stage(0, 0);
    asm volatile("s_waitcnt vmcnt(0)" ::: "memory");
    __builtin_amdgcn_s_barrier();
    int cur = 0;
    for (int k0 = 0; k0 < K; k0 += 64) {
        int kn = k0 + 64;
        if (kn < K) stage(cur ^ 1, kn);
#pragma unroll
        for (int half = 0; half < 2; half++) {
            bf8_t b = *(const bf8_t*)&Bs[cur][(wn + l16) * 64 +
                                             ((half * 4 + quad) ^ sw) * 8];
#pragma unroll
            for (int fi = 0; fi < 4; fi++) {
                bf8_t a = *(const bf8_t*)&As[cur][(fi * 16 + l16) * 64 +
                                                  ((half * 4 + quad) ^ sw) * 8];
                acc[fi] = __builtin_amdgcn_mfma_f32_16x16x32_bf16(a, b,
                                                                  acc[fi],
                                                                  0, 0, 0);
            }
        }
        asm volatile("s_waitcnt vmcnt(0)" ::: "memory");
        __builtin_amdgcn_s_barrier();
        cur ^= 1;
    }
    const void* Bias = jb.Bias[slot];
    float scale = jb.scale[slot];
    float* O = jb.Out[slot];
    short* Ob = jb.OutBf[slot];
    const float* Res = jb.Res;
    const void* ResAny = jb.ResAny;
    int Nper = jb.Nper;
    int relu = jb.relu;
    int n = nb + wn + l16;
    float bia = ldany(Bias, n, isbf);
#pragma unroll
    for (int fi = 0; fi < 4; fi++) {
#pragma unroll
        for (int r = 0; r < 4; r++) {
            int m = mb + fi * 16 + quad * 4 + r;
            float v = (acc[fi][r] + bia) * scale;
            if (relu) v = fmaxf(v, 0.f);
            if (Res) v += Res[(size_t)m * Nper + n];
            if (ResAny) v += ldany(ResAny, (size_t)m * Nper + n, isbf);
            if (O) O[(size_t)m * Nper + n] = v;
            if (Ob) Ob[(size_t)m * Nper + n] = f2b(v);
        }
    }
}

// ---------------------------------------------------------------- ECA phase 1
__global__ __launch_bounds__(256) void k_eca1_f(
    const float* __restrict__ pcp, const float* __restrict__ pqp,
    const float* __restrict__ kp, const float* __restrict__ vp,
    float* __restrict__ pattn, float* __restrict__ L1,
    float* __restrict__ L2) {
    __shared__ float Ks[64][68];
    __shared__ float Vs[64][68];
    __shared__ float Ps[64][36];
    int bh = blockIdx.y, c = blockIdx.x;
    int b = bh >> 3, h = bh & 7;
    size_t rowbase = (size_t)b * 1024 + c * 64;
    // phase 0: pc -> Ks, pq -> Vs[0..31]
    for (int ch = threadIdx.x; ch < 1024; ch += 256) {
        int s = ch >> 4, d4 = (ch & 15) * 4;
        *(float4*)&Ks[s][d4] =
            *(const float4*)&pcp[(rowbase + s) * 512 + h * 64 + d4];
    }
    for (int ch = threadIdx.x; ch < 512; ch += 256) {
        int e = ch >> 4, d4 = (ch & 15) * 4;
        *(float4*)&Vs[e][d4] =
            *(const float4*)&pqp[(size_t)(b * 32 + e) * 512 + h * 64 + d4];
    }
    __syncthreads();
    {
        int e = threadIdx.x & 31, t0 = threadIdx.x >> 5;
        float4 a8[8] = {};
        for (int d4 = 0; d4 < 64; d4 += 4) {
            float4 v = *(const float4*)&Vs[e][d4];
#pragma unroll
            for (int rr = 0; rr < 8; rr++) {
                float4 kk = *(const float4*)&Ks[t0 + rr * 8][d4];
                fma4(a8[rr], kk, v);
            }
        }
#pragma unroll
        for (int rr = 0; rr < 8; rr++) {
            int r = t0 + rr * 8;
            float s = sum4(a8[rr]);
            float v = (s > 0.f) ? (s + log2f(1.f + exp2f(-s)))
                                : log2f(1.f + exp2f(s));
            Ps[r][e] = v;
            pattn[((size_t)bh * 1024 + c * 64 + r) * 32 + e] = v;
        }
    }
    __syncthreads();
    // phase 1: K,V chunk
    for (int ch = threadIdx.x; ch < 1024; ch += 256) {
        int s = ch >> 4, d4 = (ch & 15) * 4;
        size_t gidx = (rowbase + s) * 512 + h * 64 + d4;
        *(float4*)&Ks[s][d4] = *(const float4*)&kp[gidx];
        *(float4*)&Vs[s][d4] = *(const float4*)&vp[gidx];
    }
    __syncthreads();
    size_t lbase = ((size_t)bh * 16 + c) * 2048;
    {
        int e = threadIdx.x & 31, dd0 = (threadIdx.x >> 5) * 8;
        float4 a0 = {}, a1 = {};
        for (int s = 0; s < 64; s++) {
            float ps = Ps[s][e];
            float4 k0 = *(const float4*)&Ks[s][dd0];
            float4 k1 = *(const float4*)&Ks[s][dd0 + 4];
            fma4s(a0, k0, ps);
            fma4s(a1, k1, ps);
        }
        L1[lbase + (dd0 + 0) * 32 + e] = a0.x;
        L1[lbase + (dd0 + 1) * 32 + e] = a0.y;
        L1[lbase + (dd0 + 2) * 32 + e] = a0.z;
        L1[lbase + (dd0 + 3) * 32 + e] = a0.w;
        L1[lbase + (dd0 + 4) * 32 + e] = a1.x;
        L1[lbase + (dd0 + 5) * 32 + e] = a1.y;
        L1[lbase + (dd0 + 6) * 32 + e] = a1.z;
        L1[lbase + (dd0 + 7) * 32 + e] = a1.w;
    }
    {
        int dd = threadIdx.x & 63, e0 = (threadIdx.x >> 6) * 8;
        float4 a0 = {}, a1 = {};
        for (int s = 0; s < 64; s++) {
            float vv = Vs[s][dd];
            float4 p0 = *(const float4*)&Ps[s][e0];
            float4 p1 = *(const float4*)&Ps[s][e0 + 4];
            fma4s(a0, p0, vv);
            fma4s(a1, p1, vv);
        }
        L2[lbase + (e0 + 0) * 64 + dd] = a0.x;
        L2[lbase + (e0 + 1) * 64 + dd] = a0.y;
        L2[lbase + (e0 + 2) * 64 + dd] = a0.z;
        L2[lbase + (e0 + 3) * 64 + dd] = a0.w;
        L2[lbase + (e0 + 4) * 64 + dd] = a1.x;
        L2[lbase + (e0 + 5) * 64 + dd] = a1.y;
        L2[lbase + (e0 + 6) * 64 + dd] = a1.z;
        L2[lbase + (e0 + 7) * 64 + dd] = a1.w;
    }
}

// ---------------------------------------------------------------- chunk scan
__global__ __launch_bounds__(256) void k_scan(float* __restrict__ L1,
                                              float* __restrict__ L2) {
    int gid = blockIdx.x * 256 + threadIdx.x;  // 32768 = 16 bh * 2048
    int bh = gid >> 11, lin = gid & 2047;
    size_t base = (size_t)bh * 16 * 2048 + lin;
    float run = 0.f;
#pragma unroll
    for (int c = 0; c < 16; c++) {
        float v = L1[base + c * 2048];
        L1[base + c * 2048] = run;
        run += v;
    }
    run = 0.f;
#pragma unroll
    for (int c = 0; c < 16; c++) {
        float v = L2[base + c * 2048];
        L2[base + c * 2048] = run;
        run += v;
    }
}

// ---------------------------------------------------------------- ECA3 + MHA1
// One dispatch: blockIdx.x<16 -> eca3, else -> mha1 flash partials.
// R7: SS-L2 load FIXED (full 512-quad coverage; R4/R5 loaded only 384 ->
// SS rows 24-31 stale -> absmax creep).
__global__ __launch_bounds__(512) void k_attn_mid(
    const float* __restrict__ qp, const float* __restrict__ kp,
    const float* __restrict__ vp, const float* __restrict__ pattn,
    const float* __restrict__ L1s, const float* __restrict__ L2s,
    short* __restrict__ attnbf, const float* __restrict__ pkq,
    const float* __restrict__ pkk, const float* __restrict__ pkv,
    float* __restrict__ partC, float* __restrict__ ml) {
    __shared__ __align__(16) float smem[15616];
    int bh = blockIdx.y;
    int tid = threadIdx.x;
    int b = bh >> 3, h = bh & 7;
    if (blockIdx.x >= 16) {
        // -------- MHA1 partials (flash, 512 thr) --------
        int ks = blockIdx.x - 16;
        float (*Qs)[68] = (float(*)[68])smem;                   // 32 rows
        float (*Ks)[68] = (float(*)[68])(smem + 2176);          // 64 rows
        float (*Vs)[68] = (float(*)[68])(smem + 6528);          // 64 rows
        float (*Ps)[68] = (float(*)[68])(smem + 10880);         // 32 rows
        {
            int i = tid >> 4, d4 = (tid & 15) * 4;
            *(float4*)&Qs[i][d4] =
                *(const float4*)&pkq[(size_t)(b * 32 + i) * 512 + h * 64 + d4];
        }
        for (int ch = tid; ch < 1024; ch += 512) {
            int kk = ch >> 4, d4 = (ch & 15) * 4;
            size_t g = ((size_t)b * 1024 + ks * 64 + kk) * 512 + h * 64 + d4;
            *(float4*)&Ks[kk][d4] = *(const float4*)&pkk[g];
            *(float4*)&Vs[kk][d4] = *(const float4*)&pkv[g];
        }
        __syncthreads();
        int k = tid & 63, ig = tid >> 6;  // 8 waves x 4 rows
        float4 sa[4] = {};
        for (int d4 = 0; d4 < 64; d4 += 4) {
            float4 kk4 = *(const float4*)&Ks[k][d4];
#pragma unroll
            for (int j = 0; j < 4; j++) {
                float4 q = *(const float4*)&Qs[ig * 4 + j][d4];
                fma4(sa[j], q, kk4);
            }
        }
#pragma unroll
        for (int j = 0; j < 4; j++) {
            float s = sum4(sa[j]);
            float m = s;
#pragma unroll
            for (int off = 32; off >= 1; off >>= 1)
                m = fmaxf(m, __shfl_xor(m, off, 64));
            float e = expf(s - m);
            float l = e;
#pragma unroll
            for (int off = 32; off >= 1; off >>= 1)
                l += __shfl_xor(l, off, 64);
            Ps[ig * 4 + j][k] = e;
            if (k == 0) {
                int i = ig * 4 + j;
                ml[((size_t)bh * 16 + ks) * 64 + i * 2] = m;
                ml[((size_t)bh * 16 + ks) * 64 + i * 2 + 1] = l;
            }
        }
        __syncthreads();
        int dd = k;
        float a[4] = {};
        for (int kk4 = 0; kk4 < 64; kk4 += 4) {
            float v0 = Vs[kk4][dd], v1 = Vs[kk4 + 1][dd];
            float v2 = Vs[kk4 + 2][dd], v3 = Vs[kk4 + 3][dd];
#pragma unroll
            for (int j = 0; j < 4; j++) {
                float4 pv = *(const float4*)&Ps[ig * 4 + j][kk4];
                a[j] += pv.x * v0 + pv.y * v1 + pv.z * v2 + pv.w * v3;
            }
        }
        size_t base = ((size_t)bh * 16 + ks) * 2048;
#pragma unroll
        for (int j = 0; j < 4; j++)
            partC[base + (ig * 4 + j) * 64 + dd] = a[j];
        return;
    }
    // -------- ECA3 --------
    int c = blockIdx.x;
    float (*R0)[68] = (float(*)[68])smem;            // 64x68
    float (*R1)[68] = (float(*)[68])(smem + 4352);   // 64x68
    float (*Ps)[36] = (float(*)[36])(smem + 8704);   // 64x36
    float* SS = smem + 11008;                        // 2304
    float (*Pr)[36] = (float(*)[36])(smem + 13312);  // 64x36
    size_t rowbase = (size_t)b * 1024 + c * 64;
    for (int ch = tid; ch < 1024; ch += 512) {
        int t = ch >> 4, d4 = (ch & 15) * 4;
        size_t gidx = (rowbase + t) * 512 + h * 64 + d4;
        *(float4*)&R0[t][d4] = *(const float4*)&qp[gidx];
        *(float4*)&R1[t][d4] = *(const float4*)&kp[gidx];
    }
    {
        int t = tid >> 3, e4 = (tid & 7) * 4;
        *(float4*)&Ps[t][e4] =
            *(const float4*)&pattn[((size_t)bh * 1024 + c * 64 + t) * 32 + e4];
    }
    {
        // pre-scanned S1 (exclusive prefix) straight from global
        float4 s4 =
            *(const float4*)&L1s[((size_t)bh * 16 + c) * 2048 + tid * 4];
        int dd = tid >> 3, e4 = (tid & 7) * 4;
        *(float4*)&SS[dd * 36 + e4] = s4;
    }
    __syncthreads();
    int tx = tid & 15, ty = tid >> 4;
    float4 a1v[2][4] = {};
    float qs1[2][2] = {};
    for (int d4 = 0; d4 < 64; d4 += 4) {
        float4 q0 = *(const float4*)&R0[ty * 2][d4];
        float4 q1 = *(const float4*)&R0[ty * 2 + 1][d4];
#pragma unroll
        for (int j = 0; j < 4; j++) {
            // rows tx+16j: bank-group (tx+j) spreads over all 8 groups
            float4 kk = *(const float4*)&R1[tx + 16 * j][d4];
            fma4(a1v[0][j], q0, kk);
            fma4(a1v[1][j], q1, kk);
        }
#pragma unroll
        for (int cc = 0; cc < 4; cc++) {
            float2 s01 = *(const float2*)&SS[(d4 + cc) * 36 + tx * 2];
            float qa = getc(q0, cc), qb = getc(q1, cc);
            qs1[0][0] += qa * s01.x;
            qs1[0][1] += qa * s01.y;
            qs1[1][0] += qb * s01.x;
            qs1[1][1] += qb * s01.y;
        }
    }
    __syncthreads();
#pragma unroll
    for (int i = 0; i < 2; i++) {
#pragma unroll
        for (int j = 0; j < 4; j++)
            R0[ty * 2 + i][tx + 16 * j] = sum4(a1v[i][j]);
        Pr[ty * 2 + i][tx * 2] = qs1[i][0];
        Pr[ty * 2 + i][tx * 2 + 1] = qs1[i][1];
    }
    for (int ch = tid; ch < 1024; ch += 512) {
        int t = ch >> 4, d4 = (ch & 15) * 4;
        *(float4*)&R1[t][d4] =
            *(const float4*)&vp[(rowbase + t) * 512 + h * 64 + d4];
    }
    __syncthreads();
    {
        // aw = (prefix + lower-tri(A1) . Ps) / count, masked full-unroll
        int e = tid & 31, t0 = (tid >> 5) * 4;
        float sacc[4];
#pragma unroll
        for (int k2 = 0; k2 < 4; k2++) sacc[k2] = Pr[t0 + k2][e];
#pragma unroll
        for (int s2 = 0; s2 < 64; s2++) {
            float p = Ps[s2][e];
#pragma unroll
            for (int k2 = 0; k2 < 4; k2++) {
                float w = R0[t0 + k2][s2];
                sacc[k2] += (s2 <= t0 + k2) ? w * p : 0.f;
            }
        }
#pragma unroll
        for (int k2 = 0; k2 < 4; k2++)
            Pr[t0 + k2][e] = sacc[k2] / (float)(c * 64 + t0 + k2 + 1);
    }
    __syncthreads();
    if (tid < 64) {
        float m = -1e30f;
        for (int e = 0; e < 32; e++) m = fmaxf(m, Pr[tid][e]);
        float sum = 0.f;
        for (int e = 0; e < 32; e++) {
            float ex = expf(Pr[tid][e] - m);
            Pr[tid][e] = ex;
            sum += ex;
        }
        float inv = 1.f / sum;
        for (int e = 0; e < 32; e++) Pr[tid][e] *= inv;
    } else {
        // FIXED: FULL 512-quad coverage (448 threads, 2 passes for ch<64)
        for (int ch = tid - 64; ch < 512; ch += 448) {
            float4 s4 =
                *(const float4*)&L2s[((size_t)bh * 16 + c) * 2048 + ch * 4];
            int e = ch >> 4, d4 = (ch & 15) * 4;
            *(float4*)&SS[e * 68 + d4] = s4;
        }
    }
    __syncthreads();
    float a2r[2][4] = {};
    float ps2[2][4] = {};
    for (int e4 = 0; e4 < 32; e4 += 4) {
        float4 pr0 = *(const float4*)&Pr[ty * 2][e4];
        float4 pr1 = *(const float4*)&Pr[ty * 2 + 1][e4];
        float4 bj[4];
        float4 vv[4];
#pragma unroll
        for (int j = 0; j < 4; j++)
            bj[j] = *(const float4*)&Ps[tx + 16 * j][e4];  // remapped rows
#pragma unroll
        for (int cc = 0; cc < 4; cc++)
            vv[cc] = *(const float4*)&SS[(e4 + cc) * 68 + tx * 4];
#pragma unroll
        for (int cc = 0; cc < 4; cc++) {
            float pa = getc(pr0, cc), pb = getc(pr1, cc);
#pragma unroll
            for (int j = 0; j < 4; j++) {
                float bv_ = getc(bj[j], cc);
                float vvv = getc(vv[cc], j);
                a2r[0][j] += pa * bv_;
                a2r[1][j] += pb * bv_;
                ps2[0][j] += pa * vvv;
                ps2[1][j] += pb * vvv;
            }
        }
    }
    __syncthreads();
#pragma unroll
    for (int i = 0; i < 2; i++)
#pragma unroll
        for (int j = 0; j < 4; j++)
            R0[ty * 2 + i][tx + 16 * j] = a2r[i][j];  // remapped s-cols
    __syncthreads();
    {
        // PV: acch = ps2 + lower-tri(A2) . V, masked full-unroll, b128 V rows
        float4 acc4[2];
#pragma unroll
        for (int i = 0; i < 2; i++) {
            acc4[i].x = ps2[i][0]; acc4[i].y = ps2[i][1];
            acc4[i].z = ps2[i][2]; acc4[i].w = ps2[i][3];
        }
        int t0 = ty * 2;
#pragma unroll
        for (int s = 0; s < 64; s++) {
            float4 r = *(const float4*)&R1[s][tx * 4];
#pragma unroll
            for (int i = 0; i < 2; i++) {
                float a2v = R0[t0 + i][s];
                float m = (s <= t0 + i) ? a2v : 0.f;
                fma4s(acc4[i], r, m);
            }
        }
#pragma unroll
        for (int i = 0; i < 2; i++) {
            int t = t0 + i;
            float inv = 1.f / (float)(c * 64 + t + 1);
            short4 o;
            o.x = f2b(acc4[i].x * inv);
            o.y = f2b(acc4[i].y * inv);
            o.z = f2b(acc4[i].z * inv);
            o.w = f2b(acc4[i].w * inv);
            *(short4*)&attnbf[(rowbase + t) * 512 + h * 64 + tx * 4] = o;
        }
    }
}

// ---------------------------------------------------------------- MHA2
__global__ __launch_bounds__(256) void k_mha2(const float* __restrict__ upq,
                                              const float* __restrict__ upk,
                                              const float* __restrict__ upv,
                                              short* __restrict__ yxbf) {
    __shared__ float Ksm[32][68];
    __shared__ float Vsm[32][68];
    __shared__ float Qsm[64][68];
    __shared__ float Prm[64][36];
    int bh = blockIdx.y, c = blockIdx.x;
    int b = bh >> 3, h = bh & 7;
    for (int ch = threadIdx.x; ch < 512; ch += 256) {
        int e = ch >> 4, d4 = (ch & 15) * 4;
        size_t g = (size_t)(b * 32 + e) * 512 + h * 64 + d4;
        *(float4*)&Ksm[e][d4] = *(const float4*)&upk[g];
        *(float4*)&Vsm[e][d4] = *(const float4*)&upv[g];
    }
    for (int ch = threadIdx.x; ch < 1024; ch += 256) {
        int t = ch >> 4, d4 = (ch & 15) * 4;
        *(float4*)&Qsm[t][d4] =
            *(const float4*)&upq[((size_t)b * 1024 + c * 64 + t) * 512 +
                                 h * 64 + d4];
    }
    __syncthreads();
    int row = threadIdx.x >> 2, r = threadIdx.x & 3;
    float4 sj[8] = {};
    for (int d4 = 0; d4 < 64; d4 += 4) {
        float4 q = *(const float4*)&Qsm[row][d4];
#pragma unroll
        for (int j = 0; j < 8; j++) {
            float4 kk = *(const float4*)&Ksm[r * 8 + j][d4];
            fma4(sj[j], q, kk);
        }
    }
    float p[8];
#pragma unroll
    for (int j = 0; j < 8; j++) p[j] = sum4(sj[j]);
    float m = -1e30f;
#pragma unroll
    for (int j = 0; j < 8; j++) m = fmaxf(m, p[j]);
    m = fmaxf(m, __shfl_xor(m, 1, 64));
    m = fmaxf(m, __shfl_xor(m, 2, 64));
    float sum = 0.f;
#pragma unroll
    for (int j = 0; j < 8; j++) {
        p[j] = expf(p[j] - m);
        sum += p[j];
    }
    sum += __shfl_xor(sum, 1, 64);
    sum += __shfl_xor(sum, 2, 64);
    float inv = 1.f / sum;
#pragma unroll
    for (int j = 0; j < 8; j++) Prm[row][r * 8 + j] = p[j] * inv;
    __syncthreads();
    float4 a4[4] = {};
    for (int e = 0; e < 32; e++) {
        float pe = Prm[row][e];
#pragma unroll
        for (int j4 = 0; j4 < 4; j4++) {
            float4 v4 = *(const float4*)&Vsm[e][r * 16 + j4 * 4];
            fma4s(a4[j4], v4, pe);
        }
    }
#pragma unroll
    for (int j4 = 0; j4 < 4; j4++) {
        short4 o;
        o.x = f2b(a4[j4].x);
        o.y = f2b(a4[j4].y);
        o.z = f2b(a4[j4].z);
        o.w = f2b(a4[j4].w);
        *(short4*)&yxbf[((size_t)b * 1024 + c * 64 + row) * 512 + h * 64 +
                        r * 16 + j4 * 4] = o;
    }
}

// ---------------------------------------------------------------- LayerNorm
__global__ __launch_bounds__(256) void k_ln(
    const float* __restrict__ x, const float* __restrict__ residf,
    const void* __restrict__ residany, const void* __restrict__ gv,
    const void* __restrict__ bv, float* __restrict__ out32,
    short* __restrict__ dupbf, void* __restrict__ outany, size_t ooff,
    const int* __restrict__ flagp) {
    int isbf = *flagp;
    int wave = threadIdx.x >> 6, lane = threadIdx.x & 63;
    int row = blockIdx.x * 4 + wave;
    const float* px = x + (size_t)row * 512;
    float v[8];
#pragma unroll
    for (int j = 0; j < 8; j++) {
        int col = lane + 64 * j;
        v[j] = px[col];
        if (residf) v[j] += residf[(size_t)row * 512 + col];
        if (residany) v[j] += ldany(residany, (size_t)row * 512 + col, isbf);
    }
    float sum = 0.f;
#pragma unroll
    for (int j = 0; j < 8; j++) sum += v[j];
#pragma unroll
    for (int off = 32; off >= 1; off >>= 1) sum += __shfl_xor(sum, off, 64);
    float mean = sum * (1.f / 512.f);
    float var = 0.f;
#pragma unroll
    for (int j = 0; j < 8; j++) {
        float d = v[j] - mean;
        var += d * d;
    }
#pragma unroll
    for (int off = 32; off >= 1; off >>= 1) var += __shfl_xor(var, off, 64);
    var *= (1.f / 512.f);
    float inv = rsqrtf(var + 1e-5f);
#pragma unroll
    for (int j = 0; j < 8; j++) {
        int col = lane + 64 * j;
        float y = (v[j] - mean) * inv * ldany(gv, col, isbf) +
                  ldany(bv, col, isbf);
        size_t oidx = (size_t)row * 512 + col;
        if (out32) out32[oidx] = y;
        if (dupbf) dupbf[oidx] = f2b(y);
        if (outany) {
            if (isbf)
                ((bf16*)outany + ooff)[oidx] = __float2bfloat16(y);
            else
                ((float*)outany + ooff)[oidx] = y;
        }
    }
}

// ================================================================ launch
extern "C" void kernel_launch(void* const* d_in, const int* in_sizes, int n_in,
                              void* d_out, int out_size, void* d_ws,
                              size_t ws_size, hipStream_t stream) {
    (void)in_sizes; (void)n_in; (void)out_size; (void)ws_size;
    const void* dec_in = d_in[0];
    const void* p_in = d_in[1];
    const void* enc_in = d_in[2];

    const size_t M1 = 1048576;
    float* ws = (float*)d_ws;
    float* A_ = ws + 0 * M1;  // sa_q (eca3 q) -> yx2 fp32
    float* B_ = ws + 1 * M1;  // sa_k ; later ff1_bf zone
    float* C_ = ws + 2 * M1;  // sa_v -> up_q
    float* D_ = ws + 3 * M1;  // sa_pc -> mha1 partC -> ca_lin out
    float* E_ = ws + 4 * M1;  // bf16 zone: attn_bf / mha2_bf
    float* F_ = ws + 5 * M1;  // sa_out+resid -> ff2 out
    float* S_ = ws + 6 * M1;  // scratch
    float* pattn = S_;                  // 512K floats
    float* L1 = S_ + 524288;            // 512K
    float* L2 = S_ + 1048576;           // 512K
    float* pqp = S_ + 1572864;          // 32K
    float* pkq = S_ + 1605632;          // 32K
    float* ml = S_ + 1638400;           // 16K
    float* upk = S_ + 1671168;          // 32K
    float* upv = S_ + 1703936;          // 32K
    float* partC = D_;                  // D_ dead between eca1 and ca_lin
    int* flagp = (int*)(S_ + 1736704);
    float* PKK = ws + 14 * M1;          // pk_k proj (fp32, 1M)
    float* PKV = ws + 15 * M1;          // pk_v proj (fp32, 1M)
    // bf16 buffers (shorts)
    short* attn_bf = (short*)E_;
    short* mha2_bf = (short*)(E_ + 524288);
    short* ff1_bf = (short*)B_;                       // spans B_..C_
    short* dec_bf = (short*)(ws + 7 * M1 + 786432);
    short* enc_bf = dec_bf + M1;
    short* p_bf = enc_bf + M1;
    short* F_bf = p_bf + 32768;
    short* yp_bf = F_bf + M1;
    short* yx2_bf = yp_bf + 32768;
    short* wt = yx2_bf + M1;
    short* ff1t = wt + 13 * 262144;
    short* ff2t = ff1t + M1;
    auto WTp = [&](int wi) { return wt + (size_t)((wi - 6) / 2) * 262144; };
    auto Bv = [&](int i) { return (const void*)d_in[i]; };
    short* nb16 = nullptr;
    float* nf32 = nullptr;
    const int BIG = 0x7fffffff;

    hipStream_t S = stream;
    // 1. prep: detect + tobf (vectorized) + wtrans
    {
        WT15 w;
        for (int s = 0; s < 13; s++) w.src[s] = d_in[6 + 2 * s];
        w.src[13] = d_in[38];
        w.src[14] = d_in[40];
        k_prep<<<7456, 256, 0, S>>>(dec_in, enc_in, p_in, dec_bf, enc_bf,
                                    p_bf, w, wt, ff1t, ff2t, flagp);
    }

    // 2. G1: sa projections + p projections + pk_k/pk_v
    {
        GJobs g{};
        g.nj = 3;
        g.tail.blk0 = BIG;
        GJob& a = g.j[0];
        a.A = dec_bf;
        a.W[0] = WTp(6); a.W[1] = WTp(10); a.W[2] = WTp(12); a.W[3] = WTp(14);
        a.Bias[0] = Bv(7); a.Bias[1] = Bv(11); a.Bias[2] = Bv(13);
        a.Bias[3] = Bv(15);
        a.scale[0] = 0.125f; a.scale[1] = 1.f; a.scale[2] = 1.f;
        a.scale[3] = 1.f;
        a.Out[0] = A_; a.Out[1] = D_; a.Out[2] = B_; a.Out[3] = C_;
        a.OutBf[0] = nb16; a.OutBf[1] = nb16; a.OutBf[2] = nb16;
        a.OutBf[3] = nb16;
        a.Res = nullptr; a.ResAny = nullptr;
        a.Nper = 512; a.K = 512; a.relu = 0;
        a.gx = 32; a.nblk = 1024; a.blk0 = 0;
        GJob& b = g.j[1];
        b.A = p_bf;
        b.W[0] = WTp(8); b.W[1] = WTp(18); b.W[2] = WTp(8); b.W[3] = WTp(8);
        b.Bias[0] = Bv(9); b.Bias[1] = Bv(19); b.Bias[2] = Bv(9);
        b.Bias[3] = Bv(9);
        b.scale[0] = 0.125f; b.scale[1] = 0.125f; b.scale[2] = 0.f;
        b.scale[3] = 0.f;
        b.Out[0] = pqp; b.Out[1] = pkq; b.Out[2] = pqp; b.Out[3] = pqp;
        b.OutBf[0] = nb16; b.OutBf[1] = nb16; b.OutBf[2] = nb16;
        b.OutBf[3] = nb16;
        b.Res = nullptr; b.ResAny = nullptr;
        b.Nper = 512; b.K = 512; b.relu = 0;
        b.gx = 16; b.nblk = 16; b.blk0 = 1024;
        GJob& cj = g.j[2];
        cj.A = enc_bf;
        cj.W[0] = WTp(20); cj.W[1] = WTp(22); cj.W[2] = WTp(20);
        cj.W[3] = WTp(20);
        cj.Bias[0] = Bv(21); cj.Bias[1] = Bv(23); cj.Bias[2] = Bv(21);
        cj.Bias[3] = Bv(21);
        cj.scale[0] = 1.f; cj.scale[1] = 1.f; cj.scale[2] = 1.f;
        cj.scale[3] = 1.f;
        cj.Out[0] = PKK; cj.Out[1] = PKV; cj.Out[2] = PKK; cj.Out[3] = PKK;
        cj.OutBf[0] = nb16; cj.OutBf[1] = nb16; cj.OutBf[2] = nb16;
        cj.OutBf[3] = nb16;
        cj.Res = nullptr; cj.ResAny = nullptr;
        cj.Nper = 512; cj.K = 512; cj.relu = 0;
        cj.gx = 16; cj.nblk = 512; cj.blk0 = 1040;
        k_gemm_mfma<<<1552, 256, 0, S>>>(g, flagp);
    }
    // 3. eca1 (pattn fused)
    k_eca1_f<<<dim3(16, 16), 256, 0, S>>>(D_, pqp, B_, C_, pattn, L1, L2);
    // 3b. chunk scan (exclusive prefix)
    k_scan<<<128, 256, 0, S>>>(L1, L2);
    // 4. eca3 + mha1 partials
    k_attn_mid<<<dim3(32, 16), 512, 0, S>>>(A_, B_, C_, pattn, L1, L2,
                                            attn_bf, pkq, PKK, PKV, partC,
                                            ml);
    // 5. G2: sa_out (+dec residual) + tail: mha1 reduce + Yp LN
    {
        GJobs g{};
        g.nj = 1;
        GJob& a = g.j[0];
        a.A = attn_bf;
        a.W[0] = WTp(16); a.W[1] = WTp(16); a.W[2] = WTp(16); a.W[3] = WTp(16);
        a.Bias[0] = Bv(17); a.Bias[1] = Bv(17); a.Bias[2] = Bv(17);
        a.Bias[3] = Bv(17);
        a.scale[0] = 1.f; a.scale[1] = 1.f; a.scale[2] = 1.f; a.scale[3] = 1.f;
        a.Out[0] = F_; a.Out[1] = F_; a.Out[2] = F_; a.Out[3] = F_;
        a.OutBf[0] = F_bf; a.OutBf[1] = F_bf; a.OutBf[2] = F_bf;
        a.OutBf[3] = F_bf;
        a.Res = nullptr; a.ResAny = dec_in;
        a.Nper = 512; a.K = 512; a.relu = 0;
        a.gx = 8; a.nblk = 256; a.blk0 = 0;
        g.tail.blk0 = 256;
        g.tail.partC = partC;
        g.tail.ml = ml;
        g.tail.p_in = p_in;
        g.tail.gv = d_in[32];
        g.tail.bv = d_in[33];
        g.tail.yp_bf = yp_bf;
        g.tail.outany = d_out;
        g.tail.ooff = 1048576ull;
        k_gemm_mfma<<<320, 256, 0, S>>>(g, flagp);
    }
    // 6. G3: up_k/up_v + up_q
    {
        GJobs g{};
        g.nj = 2;
        g.tail.blk0 = BIG;
        GJob& a = g.j[0];
        a.A = yp_bf;
        a.W[0] = WTp(26); a.W[1] = WTp(28); a.W[2] = WTp(26); a.W[3] = WTp(26);
        a.Bias[0] = Bv(27); a.Bias[1] = Bv(29); a.Bias[2] = Bv(27);
        a.Bias[3] = Bv(27);
        a.scale[0] = 1.f; a.scale[1] = 1.f; a.scale[2] = 1.f; a.scale[3] = 1.f;
        a.Out[0] = upk; a.Out[1] = upv; a.Out[2] = upk; a.Out[3] = upk;
        a.OutBf[0] = nb16; a.OutBf[1] = nb16; a.OutBf[2] = nb16;
        a.OutBf[3] = nb16;
        a.Res = nullptr; a.ResAny = nullptr;
        a.Nper = 512; a.K = 512; a.relu = 0;
        a.gx = 16; a.nblk = 16; a.blk0 = 0;
        GJob& b = g.j[1];
        b.A = F_bf;
        b.W[0] = WTp(24); b.W[1] = WTp(24); b.W[2] = WTp(24); b.W[3] = WTp(24);
        b.Bias[0] = Bv(25); b.Bias[1] = Bv(25); b.Bias[2] = Bv(25);
        b.Bias[3] = Bv(25);
        b.scale[0] = 0.125f; b.scale[1] = 0.125f; b.scale[2] = 0.125f;
        b.scale[3] = 0.125f;
        b.Out[0] = C_; b.Out[1] = C_; b.Out[2] = C_; b.Out[3] = C_;
        b.OutBf[0] = nb16; b.OutBf[1] = nb16; b.OutBf[2] = nb16;
        b.OutBf[3] = nb16;
        b.Res = nullptr; b.ResAny = nullptr;
        b.Nper = 512; b.K = 512; b.relu = 0;
        b.gx = 8; b.nblk = 256; b.blk0 = 16;
        k_gemm_mfma<<<272, 256, 0, S>>>(g, flagp);
    }
    // 7. mha2
    k_mha2<<<dim3(16, 16), 256, 0, S>>>(C_, upk, upv, mha2_bf);
    // 8. G4: ca_lin
    {
        GJobs g{};
        g.nj = 1;
        g.tail.blk0 = BIG;
        GJob& a = g.j[0];
        a.A = mha2_bf;
        a.W[0] = WTp(30); a.W[1] = WTp(30); a.W[2] = WTp(30); a.W[3] = WTp(30);
        a.Bias[0] = Bv(31); a.Bias[1] = Bv(31); a.Bias[2] = Bv(31);
        a.Bias[3] = Bv(31);
        a.scale[0] = 1.f; a.scale[1] = 1.f; a.scale[2] = 1.f; a.scale[3] = 1.f;
        a.Out[0] = D_; a.Out[1] = D_; a.Out[2] = D_; a.Out[3] = D_;
        a.OutBf[0] = nb16; a.OutBf[1] = nb16; a.OutBf[2] = nb16;
        a.OutBf[3] = nb16;
        a.Res = nullptr; a.ResAny = nullptr;
        a.Nper = 512; a.K = 512; a.relu = 0;
        a.gx = 8; a.nblk = 256; a.blk0 = 0;
        k_gemm_mfma<<<256, 256, 0, S>>>(g, flagp);
    }
    // 9. LN -> yx2
    k_ln<<<2048 / 4, 256, 0, S>>>(D_, F_, nullptr, d_in[34], d_in[35], A_,
                                  yx2_bf, nullptr, 0, flagp);
    // 10. G5: ff1 + relu
    {
        GJobs g{};
        g.nj = 1;
        g.tail.blk0 = BIG;
        GJob& a = g.j[0];
        a.A = yx2_bf;
        a.W[0] = ff1t; a.W[1] = ff1t; a.W[2] = ff1t; a.W[3] = ff1t;
        a.Bias[0] = Bv(39); a.Bias[1] = Bv(39); a.Bias[2] = Bv(39);
        a.Bias[3] = Bv(39);
        a.scale[0] = 1.f; a.scale[1] = 1.f; a.scale[2] = 1.f; a.scale[3] = 1.f;
        a.Out[0] = nf32; a.Out[1] = nf32; a.Out[2] = nf32; a.Out[3] = nf32;
        a.OutBf[0] = ff1_bf; a.OutBf[1] = ff1_bf; a.OutBf[2] = ff1_bf;
        a.OutBf[3] = ff1_bf;
        a.Res = nullptr; a.ResAny = nullptr;
        a.Nper = 2048; a.K = 512; a.relu = 1;
        a.gx = 32; a.nblk = 1024; a.blk0 = 0;
        k_gemm_mfma<<<1024, 256, 0, S>>>(g, flagp);
    }
    // 11. G6: ff2
    {
        GJobs g{};
        g.nj = 1;
        g.tail.blk0 = BIG;
        GJob& a = g.j[0];
        a.A = ff1_bf;
        a.W[0] = ff2t; a.W[1] = ff2t; a.W[2] = ff2t; a.W[3] = ff2t;
        a.Bias[0] = Bv(41); a.Bias[1] = Bv(41); a.Bias[2] = Bv(41);
        a.Bias[3] = Bv(41);
        a.scale[0] = 1.f; a.scale[1] = 1.f; a.scale[2] = 1.f; a.scale[3] = 1.f;
        a.Out[0] = F_; a.Out[1] = F_; a.Out[2] = F_; a.Out[3] = F_;
        a.OutBf[0] = nb16; a.OutBf[1] = nb16; a.OutBf[2] = nb16;
        a.OutBf[3] = nb16;
        a.Res = nullptr; a.ResAny = nullptr;
        a.Nper = 512; a.K = 2048; a.relu = 0;
        a.gx = 8; a.nblk = 256; a.blk0 = 0;
        k_gemm_mfma<<<256, 256, 0, S>>>(g, flagp);
    }
    // 12. final LN
    k_ln<<<2048 / 4, 256, 0, S>>>(F_, A_, nullptr, d_in[36], d_in[37],
                                  nullptr, nullptr, d_out, 0, flagp);
}

// Round 8
// 314.199 us; speedup vs baseline: 1.1422x; 1.1422x over previous
//
#include <hip/hip_runtime.h>
#include <hip/hip_bf16.h>

typedef __hip_bfloat16 bf16;
typedef __attribute__((ext_vector_type(8))) short bf8_t;  // 8 bf16 (4 VGPR)
typedef __attribute__((ext_vector_type(4))) float f4_t;

__device__ __forceinline__ float b2f(bf16 x) { return __bfloat162float(x); }

__device__ __forceinline__ float ldany(const void* p, size_t i, int isbf) {
    return isbf ? b2f(((const bf16*)p)[i]) : ((const float*)p)[i];
}

// fp32 -> bf16 (RTN-even), bit pattern as short
__device__ __forceinline__ short f2b(float f) {
    unsigned u = __builtin_bit_cast(unsigned, f);
    u += 0x7fffu + ((u >> 16) & 1u);
    return (short)(u >> 16);
}

__device__ __forceinline__ void gload16(const short* g, short* l) {
    __builtin_amdgcn_global_load_lds(
        (const __attribute__((address_space(1))) void*)g,
        (__attribute__((address_space(3))) void*)l, 16, 0, 0);
}

__device__ __forceinline__ void fma4(float4& a, const float4& x,
                                     const float4& y) {
    a.x += x.x * y.x; a.y += x.y * y.y;
    a.z += x.z * y.z; a.w += x.w * y.w;
}
__device__ __forceinline__ void fma4s(float4& a, const float4& x, float s) {
    a.x += x.x * s; a.y += x.y * s; a.z += x.z * s; a.w += x.w * s;
}
__device__ __forceinline__ float sum4(const float4& a) {
    return (a.x + a.y) + (a.z + a.w);
}
// component select; folds to static with unrolled constant c
__device__ __forceinline__ float getc(const float4& v, int c) {
    return c == 0 ? v.x : c == 1 ? v.y : c == 2 ? v.z : v.w;
}

// ---------------------------------------------------------------- prep
// detect (per-block local) + to-bf16 (vectorized) + weight transpose.
struct WT15 {
    const void* src[15];
};

__global__ __launch_bounds__(256) void k_prep(
    const void* __restrict__ dec, const void* __restrict__ enc,
    const void* __restrict__ p, short* __restrict__ dec_bf,
    short* __restrict__ enc_bf, short* __restrict__ p_bf, WT15 w,
    short* __restrict__ wt, short* __restrict__ ff1t,
    short* __restrict__ ff2t, int* __restrict__ flagp) {
    __shared__ float T[32][33];
    __shared__ int cntS;
    if (threadIdx.x == 0) cntS = 0;
    __syncthreads();
    {
        float f = b2f(((const bf16*)dec)[threadIdx.x]);  // first 256 bf16
        float a = fabsf(f);
        int bad = (!(a < 1e10f) || (a != 0.f && a < 1e-20f)) ? 1 : 0;
#pragma unroll
        for (int off = 32; off >= 1; off >>= 1)
            bad += __shfl_xor(bad, off, 64);
        if ((threadIdx.x & 63) == 0) atomicAdd(&cntS, bad);
    }
    __syncthreads();
    int isbf = (cntS >= 3) ? 0 : 1;
    if (blockIdx.x == 0 && threadIdx.x == 0) *flagp = isbf;
    int id = blockIdx.x;
    if (id < 2080) {  // to-bf16: 2129920 elements, 4/thread vectorized
        size_t i4 = ((size_t)id * 256 + threadIdx.x) * 4;
        const void* src;
        short* dst;
        size_t idx;
        if (i4 < 1048576) { src = dec; dst = dec_bf; idx = i4; }
        else if (i4 < 2097152) { src = enc; dst = enc_bf; idx = i4 - 1048576; }
        else { src = p; dst = p_bf; idx = i4 - 2097152; }
        if (isbf) {
            *(short4*)&dst[idx] =
                ((const short4*)((const short*)src))[idx >> 2];
        } else {
            float4 f = ((const float4*)((const float*)src))[idx >> 2];
            short4 o;
            o.x = f2b(f.x); o.y = f2b(f.y); o.z = f2b(f.z); o.w = f2b(f.w);
            *(short4*)&dst[idx] = o;
        }
        return;
    }
    id -= 2080;
    const void* src;
    short* d;
    int K, N, bx, by;
    if (id < 3328) {              // 13 square 512x512 slabs
        int slab = id >> 8, rem = id & 255;
        src = w.src[slab];
        d = wt + (size_t)slab * 262144;
        K = 512; N = 512;
        bx = rem & 15; by = rem >> 4;
    } else if (id < 4352) {       // ff1
        int rem = id - 3328;
        src = w.src[13]; d = ff1t;
        K = 512; N = 2048;
        bx = rem & 63; by = rem >> 6;
    } else {                      // ff2
        int rem = id - 4352;
        src = w.src[14]; d = ff2t;
        K = 2048; N = 512;
        bx = rem & 15; by = rem >> 4;
    }
    int nb = bx * 32, kb = by * 32;
    int col = threadIdx.x & 31, row0 = threadIdx.x >> 5;
#pragma unroll
    for (int i = 0; i < 4; i++) {
        int r = row0 + i * 8;
        T[r][col] = ldany(src, (size_t)(kb + r) * N + nb + col, isbf);
    }
    __syncthreads();
#pragma unroll
    for (int i = 0; i < 4; i++) {
        int r = row0 + i * 8;
        d[(size_t)(nb + r) * K + kb + col] = f2b(T[col][r]);
    }
}

// ---------------------------------------------------------------- MFMA GEMM
// R4 structure (best measured): 2-buffer LDS, global_load_lds(16B),
// STAGE(next) -> MFMA(cur) -> vmcnt(0) -> barrier.
struct GJob {
    const short* A;
    const short* W[4];
    const void* Bias[4];
    float scale[4];
    float* Out[4];
    short* OutBf[4];
    const float* Res;
    const void* ResAny;
    int Nper, K, relu;
    int gx, nblk, blk0;
};
struct GTail {
    int blk0;
    const float* partC;
    const float* ml;
    const void* p_in;
    const void* gv;
    const void* bv;
    short* yp_bf;
    void* outany;
    unsigned long long ooff;
};
struct GJobs {
    GJob j[3];
    GTail tail;
    int nj;
};

__device__ void red_ln_dev(const GTail& T, int row, int isbf, float* red) {
    int b = row >> 5, i = row & 31;
    float v[2];
#pragma unroll
    for (int t = 0; t < 2; t++) {
        int col = (int)threadIdx.x + t * 256;
        int h = col >> 6, dd = col & 63;
        int bh = b * 8 + h;
        float M = -1e30f;
        for (int ks2 = 0; ks2 < 16; ks2++)
            M = fmaxf(M, T.ml[((size_t)bh * 16 + ks2) * 64 + i * 2]);
        float L = 0.f, acc = 0.f;
        for (int ks2 = 0; ks2 < 16; ks2++) {
            float m = T.ml[((size_t)bh * 16 + ks2) * 64 + i * 2];
            float l = T.ml[((size_t)bh * 16 + ks2) * 64 + i * 2 + 1];
            float w = expf(m - M);
            L += l * w;
            acc += T.partC[((size_t)bh * 16 + ks2) * 2048 + i * 64 + dd] * w;
        }
        float raw = acc / L;
        size_t o = (size_t)(b * 32 + i) * 512 + col;
        T.yp_bf[o] = f2b(raw);
        v[t] = raw + ldany(T.p_in, o, isbf);
    }
    int wave = threadIdx.x >> 6, lane = threadIdx.x & 63;
    float sum = v[0] + v[1];
#pragma unroll
    for (int off = 32; off >= 1; off >>= 1) sum += __shfl_xor(sum, off, 64);
    if (lane == 0) red[wave] = sum;
    __syncthreads();
    float mean = (red[0] + red[1] + red[2] + red[3]) * (1.f / 512.f);
    float var = 0.f;
#pragma unroll
    for (int t = 0; t < 2; t++) {
        float dd = v[t] - mean;
        var += dd * dd;
    }
#pragma unroll
    for (int off = 32; off >= 1; off >>= 1) var += __shfl_xor(var, off, 64);
    if (lane == 0) red[wave + 4] = var;
    __syncthreads();
    var = (red[4] + red[5] + red[6] + red[7]) * (1.f / 512.f);
    float inv = rsqrtf(var + 1e-5f);
#pragma unroll
    for (int t = 0; t < 2; t++) {
        int col = (int)threadIdx.x + t * 256;
        size_t o = (size_t)((row >> 5) * 32 + (row & 31)) * 512 + col;
        float y = (v[t] - mean) * inv * ldany(T.gv, col, isbf) +
                  ldany(T.bv, col, isbf);
        if (isbf)
            ((bf16*)T.outany + T.ooff)[o] = __float2bfloat16(y);
        else
            ((float*)T.outany + T.ooff)[o] = y;
    }
}

__global__ __launch_bounds__(256, 4) void k_gemm_mfma(
    GJobs gs, const int* __restrict__ flagp) {
    __shared__ __align__(16) short As[2][64 * 64];
    __shared__ __align__(16) short Bs[2][64 * 64];
    __shared__ float redS[8];
    int isbf = *flagp;
    int id = blockIdx.x;
    if (id >= gs.tail.blk0) {
        red_ln_dev(gs.tail, id - gs.tail.blk0, isbf, redS);
        return;
    }
    int tid = threadIdx.x;
    int wave = tid >> 6, lane = tid & 63;
    int quad = lane >> 4, l16 = lane & 15;
    int ji = 0;
    if (gs.nj > 1 && id >= gs.j[1].blk0) ji = 1;
    if (gs.nj > 2 && id >= gs.j[2].blk0) ji = 2;
    const GJob& jb = gs.j[ji];
    int lid = id - jb.blk0;
    int gx = jb.gx, nblk = jb.nblk;
    int bx, by;
    if ((nblk & 7) == 0) {
        int per = nblk >> 3;
        int id2 = (lid & 7) * per + (lid >> 3);
        by = id2 / gx;
        bx = id2 - by * gx;
    } else {
        by = lid / gx;
        bx = lid - by * gx;
    }
    int K = jb.K;
    int mb = by * 64;
    int nbg = bx * 64;
    int slot = nbg / jb.Nper;
    int nb = nbg - slot * jb.Nper;
    const short* Wt = jb.W[slot];
    const short* A = jb.A;
    int wn = wave * 16;
    f4_t acc[4] = {};

    const short* Ap = A + (size_t)mb * K;
    const short* Wp = Wt + (size_t)nb * K;
    int w8 = wave * 8;
    int lr = lane >> 3;
    int lc = ((lane & 7) ^ lr) * 8;  // swizzled short offset within row
    const short* ga0 = Ap + (size_t)(w8 + lr) * K + lc;
    const short* gb0 = Wp + (size_t)(w8 + lr) * K + lc;
    short* la0 = &As[0][w8 * 64];
    short* lb0 = &Bs[0][w8 * 64];

    auto stage = [&](int buf, int k) {
        gload16(ga0 + k, la0 + buf * 4096);
        gload16(ga0 + (size_t)32 * K + k, la0 + buf * 4096 + 32 * 64);
        gload16(gb0 + k, lb0 + buf * 4096);
        gload16(gb0 + (size_t)32 * K + k, lb0 + buf * 4096 + 32 * 64);
    };

    int sw = l16 & 7;

    stage(0, 0);
    asm volatile("s_waitcnt vmcnt(0)" ::: "memory");
    __builtin_amdgcn_s_barrier();
    int cur = 0;
    for (int k0 = 0; k0 < K; k0 += 64) {
        int kn = k0 + 64;
        if (kn < K) stage(cur ^ 1, kn);
#pragma unroll
        for (int half = 0; half < 2; half++) {
            bf8_t b = *(const bf8_t*)&Bs[cur][(wn + l16) * 64 +
                                             ((half * 4 + quad) ^ sw) * 8];
#pragma unroll
            for (int fi = 0; fi < 4; fi++) {
                bf8_t a = *(const bf8_t*)&As[cur][(fi * 16 + l16) * 64 +
                                                  ((half * 4 + quad) ^ sw) * 8];
                acc[fi] = __builtin_amdgcn_mfma_f32_16x16x32_bf16(a, b,
                                                                  acc[fi],
                                                                  0, 0, 0);
            }
        }
        asm volatile("s_waitcnt vmcnt(0)" ::: "memory");
        __builtin_amdgcn_s_barrier();
        cur ^= 1;
    }
    const void* Bias = jb.Bias[slot];
    float scale = jb.scale[slot];
    float* O = jb.Out[slot];
    short* Ob = jb.OutBf[slot];
    const float* Res = jb.Res;
    const void* ResAny = jb.ResAny;
    int Nper = jb.Nper;
    int relu = jb.relu;
    int n = nb + wn + l16;
    float bia = ldany(Bias, n, isbf);
#pragma unroll
    for (int fi = 0; fi < 4; fi++) {
#pragma unroll
        for (int r = 0; r < 4; r++) {
            int m = mb + fi * 16 + quad * 4 + r;
            float v = (acc[fi][r] + bia) * scale;
            if (relu) v = fmaxf(v, 0.f);
            if (Res) v += Res[(size_t)m * Nper + n];
            if (ResAny) v += ldany(ResAny, (size_t)m * Nper + n, isbf);
            if (O) O[(size_t)m * Nper + n] = v;
            if (Ob) Ob[(size_t)m * Nper + n] = f2b(v);
        }
    }
}

// ---------------------------------------------------------------- ECA phase 1
__global__ __launch_bounds__(256) void k_eca1_f(
    const float* __restrict__ pcp, const float* __restrict__ pqp,
    const float* __restrict__ kp, const float* __restrict__ vp,
    float* __restrict__ pattn, float* __restrict__ L1,
    float* __restrict__ L2) {
    __shared__ float Ks[64][68];
    __shared__ float Vs[64][68];
    __shared__ float Ps[64][36];
    int bh = blockIdx.y, c = blockIdx.x;
    int b = bh >> 3, h = bh & 7;
    size_t rowbase = (size_t)b * 1024 + c * 64;
    // phase 0: pc -> Ks, pq -> Vs[0..31]
    for (int ch = threadIdx.x; ch < 1024; ch += 256) {
        int s = ch >> 4, d4 = (ch & 15) * 4;
        *(float4*)&Ks[s][d4] =
            *(const float4*)&pcp[(rowbase + s) * 512 + h * 64 + d4];
    }
    for (int ch = threadIdx.x; ch < 512; ch += 256) {
        int e = ch >> 4, d4 = (ch & 15) * 4;
        *(float4*)&Vs[e][d4] =
            *(const float4*)&pqp[(size_t)(b * 32 + e) * 512 + h * 64 + d4];
    }
    __syncthreads();
    {
        int e = threadIdx.x & 31, t0 = threadIdx.x >> 5;
        float4 a8[8] = {};
        for (int d4 = 0; d4 < 64; d4 += 4) {
            float4 v = *(const float4*)&Vs[e][d4];
#pragma unroll
            for (int rr = 0; rr < 8; rr++) {
                float4 kk = *(const float4*)&Ks[t0 + rr * 8][d4];
                fma4(a8[rr], kk, v);
            }
        }
#pragma unroll
        for (int rr = 0; rr < 8; rr++) {
            int r = t0 + rr * 8;
            float s = sum4(a8[rr]);
            float v = (s > 0.f) ? (s + log2f(1.f + exp2f(-s)))
                                : log2f(1.f + exp2f(s));
            Ps[r][e] = v;
            pattn[((size_t)bh * 1024 + c * 64 + r) * 32 + e] = v;
        }
    }
    __syncthreads();
    // phase 1: K,V chunk
    for (int ch = threadIdx.x; ch < 1024; ch += 256) {
        int s = ch >> 4, d4 = (ch & 15) * 4;
        size_t gidx = (rowbase + s) * 512 + h * 64 + d4;
        *(float4*)&Ks[s][d4] = *(const float4*)&kp[gidx];
        *(float4*)&Vs[s][d4] = *(const float4*)&vp[gidx];
    }
    __syncthreads();
    size_t lbase = ((size_t)bh * 16 + c) * 2048;
    {
        int e = threadIdx.x & 31, dd0 = (threadIdx.x >> 5) * 8;
        float4 a0 = {}, a1 = {};
        for (int s = 0; s < 64; s++) {
            float ps = Ps[s][e];
            float4 k0 = *(const float4*)&Ks[s][dd0];
            float4 k1 = *(const float4*)&Ks[s][dd0 + 4];
            fma4s(a0, k0, ps);
            fma4s(a1, k1, ps);
        }
        L1[lbase + (dd0 + 0) * 32 + e] = a0.x;
        L1[lbase + (dd0 + 1) * 32 + e] = a0.y;
        L1[lbase + (dd0 + 2) * 32 + e] = a0.z;
        L1[lbase + (dd0 + 3) * 32 + e] = a0.w;
        L1[lbase + (dd0 + 4) * 32 + e] = a1.x;
        L1[lbase + (dd0 + 5) * 32 + e] = a1.y;
        L1[lbase + (dd0 + 6) * 32 + e] = a1.z;
        L1[lbase + (dd0 + 7) * 32 + e] = a1.w;
    }
    {
        int dd = threadIdx.x & 63, e0 = (threadIdx.x >> 6) * 8;
        float4 a0 = {}, a1 = {};
        for (int s = 0; s < 64; s++) {
            float vv = Vs[s][dd];
            float4 p0 = *(const float4*)&Ps[s][e0];
            float4 p1 = *(const float4*)&Ps[s][e0 + 4];
            fma4s(a0, p0, vv);
            fma4s(a1, p1, vv);
        }
        L2[lbase + (e0 + 0) * 64 + dd] = a0.x;
        L2[lbase + (e0 + 1) * 64 + dd] = a0.y;
        L2[lbase + (e0 + 2) * 64 + dd] = a0.z;
        L2[lbase + (e0 + 3) * 64 + dd] = a0.w;
        L2[lbase + (e0 + 4) * 64 + dd] = a1.x;
        L2[lbase + (e0 + 5) * 64 + dd] = a1.y;
        L2[lbase + (e0 + 6) * 64 + dd] = a1.z;
        L2[lbase + (e0 + 7) * 64 + dd] = a1.w;
    }
}

// ---------------------------------------------------------------- chunk scan
__global__ __launch_bounds__(256) void k_scan(float* __restrict__ L1,
                                              float* __restrict__ L2) {
    int gid = blockIdx.x * 256 + threadIdx.x;  // 32768 = 16 bh * 2048
    int bh = gid >> 11, lin = gid & 2047;
    size_t base = (size_t)bh * 16 * 2048 + lin;
    float run = 0.f;
#pragma unroll
    for (int c = 0; c < 16; c++) {
        float v = L1[base + c * 2048];
        L1[base + c * 2048] = run;
        run += v;
    }
    run = 0.f;
#pragma unroll
    for (int c = 0; c < 16; c++) {
        float v = L2[base + c * 2048];
        L2[base + c * 2048] = run;
        run += v;
    }
}

// ---------------------------------------------------------------- ECA3 + MHA1
// R8: 1D grid of 512. gid<256 -> eca3, gid>=256 -> mha1. This INTERLEAVES
// block types so CU i's resident pair {i, i+256} is one eca3 + one mha1
// (R7's dim3(32,16)/bx-split gave every CU two SAME-type blocks since
// 256%32==0 -> half the CUs ran two slow eca3 blocks, half idled: 14.9%
// occupancy, 70us). Also: wave-parallel softmax (8 lanes/row, was 64/512
// threads) and single-shot 512-quad SS-L2 load overlapped with the
// triangular phase.
__global__ __launch_bounds__(512) void k_attn_mid(
    const float* __restrict__ qp, const float* __restrict__ kp,
    const float* __restrict__ vp, const float* __restrict__ pattn,
    const float* __restrict__ L1s, const float* __restrict__ L2s,
    short* __restrict__ attnbf, const float* __restrict__ pkq,
    const float* __restrict__ pkk, const float* __restrict__ pkv,
    float* __restrict__ partC, float* __restrict__ ml) {
    __shared__ __align__(16) float smem[15616];
    int gid = blockIdx.x;
    int tid = threadIdx.x;
    if (gid >= 256) {
        // -------- MHA1 partials (flash, 512 thr) --------
        int gl = gid - 256;
        int bh = gl >> 4, ks = gl & 15;
        int b = bh >> 3, h = bh & 7;
        float (*Qs)[68] = (float(*)[68])smem;                   // 32 rows
        float (*Ks)[68] = (float(*)[68])(smem + 2176);          // 64 rows
        float (*Vs)[68] = (float(*)[68])(smem + 6528);          // 64 rows
        float (*Ps)[68] = (float(*)[68])(smem + 10880);         // 32 rows
        {
            int i = tid >> 4, d4 = (tid & 15) * 4;
            *(float4*)&Qs[i][d4] =
                *(const float4*)&pkq[(size_t)(b * 32 + i) * 512 + h * 64 + d4];
        }
        for (int ch = tid; ch < 1024; ch += 512) {
            int kk = ch >> 4, d4 = (ch & 15) * 4;
            size_t g = ((size_t)b * 1024 + ks * 64 + kk) * 512 + h * 64 + d4;
            *(float4*)&Ks[kk][d4] = *(const float4*)&pkk[g];
            *(float4*)&Vs[kk][d4] = *(const float4*)&pkv[g];
        }
        __syncthreads();
        int k = tid & 63, ig = tid >> 6;  // 8 waves x 4 rows
        float4 sa[4] = {};
        for (int d4 = 0; d4 < 64; d4 += 4) {
            float4 kk4 = *(const float4*)&Ks[k][d4];
#pragma unroll
            for (int j = 0; j < 4; j++) {
                float4 q = *(const float4*)&Qs[ig * 4 + j][d4];
                fma4(sa[j], q, kk4);
            }
        }
#pragma unroll
        for (int j = 0; j < 4; j++) {
            float s = sum4(sa[j]);
            float m = s;
#pragma unroll
            for (int off = 32; off >= 1; off >>= 1)
                m = fmaxf(m, __shfl_xor(m, off, 64));
            float e = expf(s - m);
            float l = e;
#pragma unroll
            for (int off = 32; off >= 1; off >>= 1)
                l += __shfl_xor(l, off, 64);
            Ps[ig * 4 + j][k] = e;
            if (k == 0) {
                int i = ig * 4 + j;
                ml[((size_t)bh * 16 + ks) * 64 + i * 2] = m;
                ml[((size_t)bh * 16 + ks) * 64 + i * 2 + 1] = l;
            }
        }
        __syncthreads();
        int dd = k;
        float a[4] = {};
        for (int kk4 = 0; kk4 < 64; kk4 += 4) {
            float v0 = Vs[kk4][dd], v1 = Vs[kk4 + 1][dd];
            float v2 = Vs[kk4 + 2][dd], v3 = Vs[kk4 + 3][dd];
#pragma unroll
            for (int j = 0; j < 4; j++) {
                float4 pv = *(const float4*)&Ps[ig * 4 + j][kk4];
                a[j] += pv.x * v0 + pv.y * v1 + pv.z * v2 + pv.w * v3;
            }
        }
        size_t base = ((size_t)bh * 16 + ks) * 2048;
#pragma unroll
        for (int j = 0; j < 4; j++)
            partC[base + (ig * 4 + j) * 64 + dd] = a[j];
        return;
    }
    // -------- ECA3 --------
    int bh = gid >> 4, c = gid & 15;
    int b = bh >> 3, h = bh & 7;
    float (*R0)[68] = (float(*)[68])smem;            // 64x68
    float (*R1)[68] = (float(*)[68])(smem + 4352);   // 64x68
    float (*Ps)[36] = (float(*)[36])(smem + 8704);   // 64x36
    float* SS = smem + 11008;                        // 2304
    float (*Pr)[36] = (float(*)[36])(smem + 13312);  // 64x36
    size_t rowbase = (size_t)b * 1024 + c * 64;
    for (int ch = tid; ch < 1024; ch += 512) {
        int t = ch >> 4, d4 = (ch & 15) * 4;
        size_t gidx = (rowbase + t) * 512 + h * 64 + d4;
        *(float4*)&R0[t][d4] = *(const float4*)&qp[gidx];
        *(float4*)&R1[t][d4] = *(const float4*)&kp[gidx];
    }
    {
        int t = tid >> 3, e4 = (tid & 7) * 4;
        *(float4*)&Ps[t][e4] =
            *(const float4*)&pattn[((size_t)bh * 1024 + c * 64 + t) * 32 + e4];
    }
    {
        // pre-scanned S1 (exclusive prefix) straight from global
        float4 s4 =
            *(const float4*)&L1s[((size_t)bh * 16 + c) * 2048 + tid * 4];
        int dd = tid >> 3, e4 = (tid & 7) * 4;
        *(float4*)&SS[dd * 36 + e4] = s4;
    }
    __syncthreads();
    int tx = tid & 15, ty = tid >> 4;
    float4 a1v[2][4] = {};
    float qs1[2][2] = {};
    for (int d4 = 0; d4 < 64; d4 += 4) {
        float4 q0 = *(const float4*)&R0[ty * 2][d4];
        float4 q1 = *(const float4*)&R0[ty * 2 + 1][d4];
#pragma unroll
        for (int j = 0; j < 4; j++) {
            // rows tx+16j: bank-group spreads over all 8 groups
            float4 kk = *(const float4*)&R1[tx + 16 * j][d4];
            fma4(a1v[0][j], q0, kk);
            fma4(a1v[1][j], q1, kk);
        }
#pragma unroll
        for (int cc = 0; cc < 4; cc++) {
            float2 s01 = *(const float2*)&SS[(d4 + cc) * 36 + tx * 2];
            float qa = getc(q0, cc), qb = getc(q1, cc);
            qs1[0][0] += qa * s01.x;
            qs1[0][1] += qa * s01.y;
            qs1[1][0] += qb * s01.x;
            qs1[1][1] += qb * s01.y;
        }
    }
    __syncthreads();
    // A1 writeback + qs1 seed; V load; SS-L2 load (single shot, all 512
    // threads = exactly 512 quads, overlaps the triangular phase).
#pragma unroll
    for (int i = 0; i < 2; i++) {
#pragma unroll
        for (int j = 0; j < 4; j++)
            R0[ty * 2 + i][tx + 16 * j] = sum4(a1v[i][j]);
        Pr[ty * 2 + i][tx * 2] = qs1[i][0];
        Pr[ty * 2 + i][tx * 2 + 1] = qs1[i][1];
    }
    for (int ch = tid; ch < 1024; ch += 512) {
        int t = ch >> 4, d4 = (ch & 15) * 4;
        *(float4*)&R1[t][d4] =
            *(const float4*)&vp[(rowbase + t) * 512 + h * 64 + d4];
    }
    {
        float4 s4 =
            *(const float4*)&L2s[((size_t)bh * 16 + c) * 2048 + tid * 4];
        int e = tid >> 4, d4 = (tid & 15) * 4;
        *(float4*)&SS[e * 68 + d4] = s4;
    }
    __syncthreads();
    {
        // aw = (prefix + lower-tri(A1) . Ps) / count, masked full-unroll
        int e = tid & 31, t0 = (tid >> 5) * 4;
        float sacc[4];
#pragma unroll
        for (int k2 = 0; k2 < 4; k2++) sacc[k2] = Pr[t0 + k2][e];
#pragma unroll
        for (int s2 = 0; s2 < 64; s2++) {
            float p = Ps[s2][e];
#pragma unroll
            for (int k2 = 0; k2 < 4; k2++) {
                float w = R0[t0 + k2][s2];
                sacc[k2] += (s2 <= t0 + k2) ? w * p : 0.f;
            }
        }
#pragma unroll
        for (int k2 = 0; k2 < 4; k2++)
            Pr[t0 + k2][e] = sacc[k2] / (float)(c * 64 + t0 + k2 + 1);
    }
    __syncthreads();
    {
        // wave-parallel softmax: 8 lanes/row x 4 elems (was 64/512 threads)
        int row = tid >> 3, sub = tid & 7;
        float4 pv = *(const float4*)&Pr[row][sub * 4];
        float m = fmaxf(fmaxf(pv.x, pv.y), fmaxf(pv.z, pv.w));
#pragma unroll
        for (int off = 4; off >= 1; off >>= 1)
            m = fmaxf(m, __shfl_xor(m, off, 64));
        pv.x = expf(pv.x - m);
        pv.y = expf(pv.y - m);
        pv.z = expf(pv.z - m);
        pv.w = expf(pv.w - m);
        float sum = sum4(pv);
#pragma unroll
        for (int off = 4; off >= 1; off >>= 1)
            sum += __shfl_xor(sum, off, 64);
        float inv = 1.f / sum;
        pv.x *= inv; pv.y *= inv; pv.z *= inv; pv.w *= inv;
        *(float4*)&Pr[row][sub * 4] = pv;
    }
    __syncthreads();
    float a2r[2][4] = {};
    float ps2[2][4] = {};
    for (int e4 = 0; e4 < 32; e4 += 4) {
        float4 pr0 = *(const float4*)&Pr[ty * 2][e4];
        float4 pr1 = *(const float4*)&Pr[ty * 2 + 1][e4];
        float4 bj[4];
        float4 vv[4];
#pragma unroll
        for (int j = 0; j < 4; j++)
            bj[j] = *(const float4*)&Ps[tx + 16 * j][e4];  // remapped rows
#pragma unroll
        for (int cc = 0; cc < 4; cc++)
            vv[cc] = *(const float4*)&SS[(e4 + cc) * 68 + tx * 4];
#pragma unroll
        for (int cc = 0; cc < 4; cc++) {
            float pa = getc(pr0, cc), pb = getc(pr1, cc);
#pragma unroll
            for (int j = 0; j < 4; j++) {
                float bv_ = getc(bj[j], cc);
                float vvv = getc(vv[cc], j);
                a2r[0][j] += pa * bv_;
                a2r[1][j] += pb * bv_;
                ps2[0][j] += pa * vvv;
                ps2[1][j] += pb * vvv;
            }
        }
    }
    __syncthreads();
#pragma unroll
    for (int i = 0; i < 2; i++)
#pragma unroll
        for (int j = 0; j < 4; j++)
            R0[ty * 2 + i][tx + 16 * j] = a2r[i][j];  // remapped s-cols
    __syncthreads();
    {
        // PV: acch = ps2 + lower-tri(A2) . V, masked full-unroll, b128 V rows
        float4 acc4[2];
#pragma unroll
        for (int i = 0; i < 2; i++) {
            acc4[i].x = ps2[i][0]; acc4[i].y = ps2[i][1];
            acc4[i].z = ps2[i][2]; acc4[i].w = ps2[i][3];
        }
        int t0 = ty * 2;
#pragma unroll
        for (int s = 0; s < 64; s++) {
            float4 r = *(const float4*)&R1[s][tx * 4];
#pragma unroll
            for (int i = 0; i < 2; i++) {
                float a2v = R0[t0 + i][s];
                float m = (s <= t0 + i) ? a2v : 0.f;
                fma4s(acc4[i], r, m);
            }
        }
#pragma unroll
        for (int i = 0; i < 2; i++) {
            int t = t0 + i;
            float inv = 1.f / (float)(c * 64 + t + 1);
            short4 o;
            o.x = f2b(acc4[i].x * inv);
            o.y = f2b(acc4[i].y * inv);
            o.z = f2b(acc4[i].z * inv);
            o.w = f2b(acc4[i].w * inv);
            *(short4*)&attnbf[(rowbase + t) * 512 + h * 64 + tx * 4] = o;
        }
    }
}

// ---------------------------------------------------------------- MHA2
__global__ __launch_bounds__(256) void k_mha2(const float* __restrict__ upq,
                                              const float* __restrict__ upk,
                                              const float* __restrict__ upv,
                                              short* __restrict__ yxbf) {
    __shared__ float Ksm[32][68];
    __shared__ float Vsm[32][68];
    __shared__ float Qsm[64][68];
    __shared__ float Prm[64][36];
    int bh = blockIdx.y, c = blockIdx.x;
    int b = bh >> 3, h = bh & 7;
    for (int ch = threadIdx.x; ch < 512; ch += 256) {
        int e = ch >> 4, d4 = (ch & 15) * 4;
        size_t g = (size_t)(b * 32 + e) * 512 + h * 64 + d4;
        *(float4*)&Ksm[e][d4] = *(const float4*)&upk[g];
        *(float4*)&Vsm[e][d4] = *(const float4*)&upv[g];
    }
    for (int ch = threadIdx.x; ch < 1024; ch += 256) {
        int t = ch >> 4, d4 = (ch & 15) * 4;
        *(float4*)&Qsm[t][d4] =
            *(const float4*)&upq[((size_t)b * 1024 + c * 64 + t) * 512 +
                                 h * 64 + d4];
    }
    __syncthreads();
    int row = threadIdx.x >> 2, r = threadIdx.x & 3;
    float4 sj[8] = {};
    for (int d4 = 0; d4 < 64; d4 += 4) {
        float4 q = *(const float4*)&Qsm[row][d4];
#pragma unroll
        for (int j = 0; j < 8; j++) {
            float4 kk = *(const float4*)&Ksm[r * 8 + j][d4];
            fma4(sj[j], q, kk);
        }
    }
    float p[8];
#pragma unroll
    for (int j = 0; j < 8; j++) p[j] = sum4(sj[j]);
    float m = -1e30f;
#pragma unroll
    for (int j = 0; j < 8; j++) m = fmaxf(m, p[j]);
    m = fmaxf(m, __shfl_xor(m, 1, 64));
    m = fmaxf(m, __shfl_xor(m, 2, 64));
    float sum = 0.f;
#pragma unroll
    for (int j = 0; j < 8; j++) {
        p[j] = expf(p[j] - m);
        sum += p[j];
    }
    sum += __shfl_xor(sum, 1, 64);
    sum += __shfl_xor(sum, 2, 64);
    float inv = 1.f / sum;
#pragma unroll
    for (int j = 0; j < 8; j++) Prm[row][r * 8 + j] = p[j] * inv;
    __syncthreads();
    float4 a4[4] = {};
    for (int e = 0; e < 32; e++) {
        float pe = Prm[row][e];
#pragma unroll
        for (int j4 = 0; j4 < 4; j4++) {
            float4 v4 = *(const float4*)&Vsm[e][r * 16 + j4 * 4];
            fma4s(a4[j4], v4, pe);
        }
    }
#pragma unroll
    for (int j4 = 0; j4 < 4; j4++) {
        short4 o;
        o.x = f2b(a4[j4].x);
        o.y = f2b(a4[j4].y);
        o.z = f2b(a4[j4].z);
        o.w = f2b(a4[j4].w);
        *(short4*)&yxbf[((size_t)b * 1024 + c * 64 + row) * 512 + h * 64 +
                        r * 16 + j4 * 4] = o;
    }
}

// ---------------------------------------------------------------- LayerNorm
__global__ __launch_bounds__(256) void k_ln(
    const float* __restrict__ x, const float* __restrict__ residf,
    const void* __restrict__ residany, const void* __restrict__ gv,
    const void* __restrict__ bv, float* __restrict__ out32,
    short* __restrict__ dupbf, void* __restrict__ outany, size_t ooff,
    const int* __restrict__ flagp) {
    int isbf = *flagp;
    int wave = threadIdx.x >> 6, lane = threadIdx.x & 63;
    int row = blockIdx.x * 4 + wave;
    const float* px = x + (size_t)row * 512;
    float v[8];
#pragma unroll
    for (int j = 0; j < 8; j++) {
        int col = lane + 64 * j;
        v[j] = px[col];
        if (residf) v[j] += residf[(size_t)row * 512 + col];
        if (residany) v[j] += ldany(residany, (size_t)row * 512 + col, isbf);
    }
    float sum = 0.f;
#pragma unroll
    for (int j = 0; j < 8; j++) sum += v[j];
#pragma unroll
    for (int off = 32; off >= 1; off >>= 1) sum += __shfl_xor(sum, off, 64);
    float mean = sum * (1.f / 512.f);
    float var = 0.f;
#pragma unroll
    for (int j = 0; j < 8; j++) {
        float d = v[j] - mean;
        var += d * d;
    }
#pragma unroll
    for (int off = 32; off >= 1; off >>= 1) var += __shfl_xor(var, off, 64);
    var *= (1.f / 512.f);
    float inv = rsqrtf(var + 1e-5f);
#pragma unroll
    for (int j = 0; j < 8; j++) {
        int col = lane + 64 * j;
        float y = (v[j] - mean) * inv * ldany(gv, col, isbf) +
                  ldany(bv, col, isbf);
        size_t oidx = (size_t)row * 512 + col;
        if (out32) out32[oidx] = y;
        if (dupbf) dupbf[oidx] = f2b(y);
        if (outany) {
            if (isbf)
                ((bf16*)outany + ooff)[oidx] = __float2bfloat16(y);
            else
                ((float*)outany + ooff)[oidx] = y;
        }
    }
}

// ================================================================ launch
extern "C" void kernel_launch(void* const* d_in, const int* in_sizes, int n_in,
                              void* d_out, int out_size, void* d_ws,
                              size_t ws_size, hipStream_t stream) {
    (void)in_sizes; (void)n_in; (void)out_size; (void)ws_size;
    const void* dec_in = d_in[0];
    const void* p_in = d_in[1];
    const void* enc_in = d_in[2];

    const size_t M1 = 1048576;
    float* ws = (float*)d_ws;
    float* A_ = ws + 0 * M1;  // sa_q (eca3 q) -> yx2 fp32
    float* B_ = ws + 1 * M1;  // sa_k ; later ff1_bf zone
    float* C_ = ws + 2 * M1;  // sa_v -> up_q
    float* D_ = ws + 3 * M1;  // sa_pc -> mha1 partC -> ca_lin out
    float* E_ = ws + 4 * M1;  // bf16 zone: attn_bf / mha2_bf
    float* F_ = ws + 5 * M1;  // sa_out+resid -> ff2 out
    float* S_ = ws + 6 * M1;  // scratch
    float* pattn = S_;                  // 512K floats
    float* L1 = S_ + 524288;            // 512K
    float* L2 = S_ + 1048576;           // 512K
    float* pqp = S_ + 1572864;          // 32K
    float* pkq = S_ + 1605632;          // 32K
    float* ml = S_ + 1638400;           // 16K
    float* upk = S_ + 1671168;          // 32K
    float* upv = S_ + 1703936;          // 32K
    float* partC = D_;                  // D_ dead between eca1 and ca_lin
    int* flagp = (int*)(S_ + 1736704);
    float* PKK = ws + 14 * M1;          // pk_k proj (fp32, 1M)
    float* PKV = ws + 15 * M1;          // pk_v proj (fp32, 1M)
    // bf16 buffers (shorts)
    short* attn_bf = (short*)E_;
    short* mha2_bf = (short*)(E_ + 524288);
    short* ff1_bf = (short*)B_;                       // spans B_..C_
    short* dec_bf = (short*)(ws + 7 * M1 + 786432);
    short* enc_bf = dec_bf + M1;
    short* p_bf = enc_bf + M1;
    short* F_bf = p_bf + 32768;
    short* yp_bf = F_bf + M1;
    short* yx2_bf = yp_bf + 32768;
    short* wt = yx2_bf + M1;
    short* ff1t = wt + 13 * 262144;
    short* ff2t = ff1t + M1;
    auto WTp = [&](int wi) { return wt + (size_t)((wi - 6) / 2) * 262144; };
    auto Bv = [&](int i) { return (const void*)d_in[i]; };
    short* nb16 = nullptr;
    float* nf32 = nullptr;
    const int BIG = 0x7fffffff;

    hipStream_t S = stream;
    // 1. prep: detect + tobf (vectorized) + wtrans
    {
        WT15 w;
        for (int s = 0; s < 13; s++) w.src[s] = d_in[6 + 2 * s];
        w.src[13] = d_in[38];
        w.src[14] = d_in[40];
        k_prep<<<7456, 256, 0, S>>>(dec_in, enc_in, p_in, dec_bf, enc_bf,
                                    p_bf, w, wt, ff1t, ff2t, flagp);
    }

    // 2. G1: sa projections + p projections + pk_k/pk_v
    {
        GJobs g{};
        g.nj = 3;
        g.tail.blk0 = BIG;
        GJob& a = g.j[0];
        a.A = dec_bf;
        a.W[0] = WTp(6); a.W[1] = WTp(10); a.W[2] = WTp(12); a.W[3] = WTp(14);
        a.Bias[0] = Bv(7); a.Bias[1] = Bv(11); a.Bias[2] = Bv(13);
        a.Bias[3] = Bv(15);
        a.scale[0] = 0.125f; a.scale[1] = 1.f; a.scale[2] = 1.f;
        a.scale[3] = 1.f;
        a.Out[0] = A_; a.Out[1] = D_; a.Out[2] = B_; a.Out[3] = C_;
        a.OutBf[0] = nb16; a.OutBf[1] = nb16; a.OutBf[2] = nb16;
        a.OutBf[3] = nb16;
        a.Res = nullptr; a.ResAny = nullptr;
        a.Nper = 512; a.K = 512; a.relu = 0;
        a.gx = 32; a.nblk = 1024; a.blk0 = 0;
        GJob& b = g.j[1];
        b.A = p_bf;
        b.W[0] = WTp(8); b.W[1] = WTp(18); b.W[2] = WTp(8); b.W[3] = WTp(8);
        b.Bias[0] = Bv(9); b.Bias[1] = Bv(19); b.Bias[2] = Bv(9);
        b.Bias[3] = Bv(9);
        b.scale[0] = 0.125f; b.scale[1] = 0.125f; b.scale[2] = 0.f;
        b.scale[3] = 0.f;
        b.Out[0] = pqp; b.Out[1] = pkq; b.Out[2] = pqp; b.Out[3] = pqp;
        b.OutBf[0] = nb16; b.OutBf[1] = nb16; b.OutBf[2] = nb16;
        b.OutBf[3] = nb16;
        b.Res = nullptr; b.ResAny = nullptr;
        b.Nper = 512; b.K = 512; b.relu = 0;
        b.gx = 16; b.nblk = 16; b.blk0 = 1024;
        GJob& cj = g.j[2];
        cj.A = enc_bf;
        cj.W[0] = WTp(20); cj.W[1] = WTp(22); cj.W[2] = WTp(20);
        cj.W[3] = WTp(20);
        cj.Bias[0] = Bv(21); cj.Bias[1] = Bv(23); cj.Bias[2] = Bv(21);
        cj.Bias[3] = Bv(21);
        cj.scale[0] = 1.f; cj.scale[1] = 1.f; cj.scale[2] = 1.f;
        cj.scale[3] = 1.f;
        cj.Out[0] = PKK; cj.Out[1] = PKV; cj.Out[2] = PKK; cj.Out[3] = PKK;
        cj.OutBf[0] = nb16; cj.OutBf[1] = nb16; cj.OutBf[2] = nb16;
        cj.OutBf[3] = nb16;
        cj.Res = nullptr; cj.ResAny = nullptr;
        cj.Nper = 512; cj.K = 512; cj.relu = 0;
        cj.gx = 16; cj.nblk = 512; cj.blk0 = 1040;
        k_gemm_mfma<<<1552, 256, 0, S>>>(g, flagp);
    }
    // 3. eca1 (pattn fused)
    k_eca1_f<<<dim3(16, 16), 256, 0, S>>>(D_, pqp, B_, C_, pattn, L1, L2);
    // 3b. chunk scan (exclusive prefix)
    k_scan<<<128, 256, 0, S>>>(L1, L2);
    // 4. eca3 + mha1 partials (1D grid, type-interleaved pairing)
    k_attn_mid<<<512, 512, 0, S>>>(A_, B_, C_, pattn, L1, L2, attn_bf, pkq,
                                   PKK, PKV, partC, ml);
    // 5. G2: sa_out (+dec residual) + tail: mha1 reduce + Yp LN
    {
        GJobs g{};
        g.nj = 1;
        GJob& a = g.j[0];
        a.A = attn_bf;
        a.W[0] = WTp(16); a.W[1] = WTp(16); a.W[2] = WTp(16); a.W[3] = WTp(16);
        a.Bias[0] = Bv(17); a.Bias[1] = Bv(17); a.Bias[2] = Bv(17);
        a.Bias[3] = Bv(17);
        a.scale[0] = 1.f; a.scale[1] = 1.f; a.scale[2] = 1.f; a.scale[3] = 1.f;
        a.Out[0] = F_; a.Out[1] = F_; a.Out[2] = F_; a.Out[3] = F_;
        a.OutBf[0] = F_bf; a.OutBf[1] = F_bf; a.OutBf[2] = F_bf;
        a.OutBf[3] = F_bf;
        a.Res = nullptr; a.ResAny = dec_in;
        a.Nper = 512; a.K = 512; a.relu = 0;
        a.gx = 8; a.nblk = 256; a.blk0 = 0;
        g.tail.blk0 = 256;
        g.tail.partC = partC;
        g.tail.ml = ml;
        g.tail.p_in = p_in;
        g.tail.gv = d_in[32];
        g.tail.bv = d_in[33];
        g.tail.yp_bf = yp_bf;
        g.tail.outany = d_out;
        g.tail.ooff = 1048576ull;
        k_gemm_mfma<<<320, 256, 0, S>>>(g, flagp);
    }
    // 6. G3: up_k/up_v + up_q
    {
        GJobs g{};
        g.nj = 2;
        g.tail.blk0 = BIG;
        GJob& a = g.j[0];
        a.A = yp_bf;
        a.W[0] = WTp(26); a.W[1] = WTp(28); a.W[2] = WTp(26); a.W[3] = WTp(26);
        a.Bias[0] = Bv(27); a.Bias[1] = Bv(29); a.Bias[2] = Bv(27);
        a.Bias[3] = Bv(27);
        a.scale[0] = 1.f; a.scale[1] = 1.f; a.scale[2] = 1.f; a.scale[3] = 1.f;
        a.Out[0] = upk; a.Out[1] = upv; a.Out[2] = upk; a.Out[3] = upk;
        a.OutBf[0] = nb16; a.OutBf[1] = nb16; a.OutBf[2] = nb16;
        a.OutBf[3] = nb16;
        a.Res = nullptr; a.ResAny = nullptr;
        a.Nper = 512; a.K = 512; a.relu = 0;
        a.gx = 16; a.nblk = 16; a.blk0 = 0;
        GJob& b = g.j[1];
        b.A = F_bf;
        b.W[0] = WTp(24); b.W[1] = WTp(24); b.W[2] = WTp(24); b.W[3] = WTp(24);
        b.Bias[0] = Bv(25); b.Bias[1] = Bv(25); b.Bias[2] = Bv(25);
        b.Bias[3] = Bv(25);
        b.scale[0] = 0.125f; b.scale[1] = 0.125f; b.scale[2] = 0.125f;
        b.scale[3] = 0.125f;
        b.Out[0] = C_; b.Out[1] = C_; b.Out[2] = C_; b.Out[3] = C_;
        b.OutBf[0] = nb16; b.OutBf[1] = nb16; b.OutBf[2] = nb16;
        b.OutBf[3] = nb16;
        b.Res = nullptr; b.ResAny = nullptr;
        b.Nper = 512; b.K = 512; b.relu = 0;
        b.gx = 8; b.nblk = 256; b.blk0 = 16;
        k_gemm_mfma<<<272, 256, 0, S>>>(g, flagp);
    }
    // 7. mha2
    k_mha2<<<dim3(16, 16), 256, 0, S>>>(C_, upk, upv, mha2_bf);
    // 8. G4: ca_lin
    {
        GJobs g{};
        g.nj = 1;
        g.tail.blk0 = BIG;
        GJob& a = g.j[0];
        a.A = mha2_bf;
        a.W[0] = WTp(30); a.W[1] = WTp(30); a.W[2] = WTp(30); a.W[3] = WTp(30);
        a.Bias[0] = Bv(31); a.Bias[1] = Bv(31); a.Bias[2] = Bv(31);
        a.Bias[3] = Bv(31);
        a.scale[0] = 1.f; a.scale[1] = 1.f; a.scale[2] = 1.f; a.scale[3] = 1.f;
        a.Out[0] = D_; a.Out[1] = D_; a.Out[2] = D_; a.Out[3] = D_;
        a.OutBf[0] = nb16; a.OutBf[1] = nb16; a.OutBf[2] = nb16;
        a.OutBf[3] = nb16;
        a.Res = nullptr; a.ResAny = nullptr;
        a.Nper = 512; a.K = 512; a.relu = 0;
        a.gx = 8; a.nblk = 256; a.blk0 = 0;
        k_gemm_mfma<<<256, 256, 0, S>>>(g, flagp);
    }
    // 9. LN -> yx2
    k_ln<<<2048 / 4, 256, 0, S>>>(D_, F_, nullptr, d_in[34], d_in[35], A_,
                                  yx2_bf, nullptr, 0, flagp);
    // 10. G5: ff1 + relu
    {
        GJobs g{};
        g.nj = 1;
        g.tail.blk0 = BIG;
        GJob& a = g.j[0];
        a.A = yx2_bf;
        a.W[0] = ff1t; a.W[1] = ff1t; a.W[2] = ff1t; a.W[3] = ff1t;
        a.Bias[0] = Bv(39); a.Bias[1] = Bv(39); a.Bias[2] = Bv(39);
        a.Bias[3] = Bv(39);
        a.scale[0] = 1.f; a.scale[1] = 1.f; a.scale[2] = 1.f; a.scale[3] = 1.f;
        a.Out[0] = nf32; a.Out[1] = nf32; a.Out[2] = nf32; a.Out[3] = nf32;
        a.OutBf[0] = ff1_bf; a.OutBf[1] = ff1_bf; a.OutBf[2] = ff1_bf;
        a.OutBf[3] = ff1_bf;
        a.Res = nullptr; a.ResAny = nullptr;
        a.Nper = 2048; a.K = 512; a.relu = 1;
        a.gx = 32; a.nblk = 1024; a.blk0 = 0;
        k_gemm_mfma<<<1024, 256, 0, S>>>(g, flagp);
    }
    // 11. G6: ff2
    {
        GJobs g{};
        g.nj = 1;
        g.tail.blk0 = BIG;
        GJob& a = g.j[0];
        a.A = ff1_bf;
        a.W[0] = ff2t; a.W[1] = ff2t; a.W[2] = ff2t; a.W[3] = ff2t;
        a.Bias[0] = Bv(41); a.Bias[1] = Bv(41); a.Bias[2] = Bv(41);
        a.Bias[3] = Bv(41);
        a.scale[0] = 1.f; a.scale[1] = 1.f; a.scale[2] = 1.f; a.scale[3] = 1.f;
        a.Out[0] = F_; a.Out[1] = F_; a.Out[2] = F_; a.Out[3] = F_;
        a.OutBf[0] = nb16; a.OutBf[1] = nb16; a.OutBf[2] = nb16;
        a.OutBf[3] = nb16;
        a.Res = nullptr; a.ResAny = nullptr;
        a.Nper = 512; a.K = 2048; a.relu = 0;
        a.gx = 8; a.nblk = 256; a.blk0 = 0;
        k_gemm_mfma<<<256, 256, 0, S>>>(g, flagp);
    }
    // 12. final LN
    k_ln<<<2048 / 4, 256, 0, S>>>(F_, A_, nullptr, d_in[36], d_in[37],
                                  nullptr, nullptr, d_out, 0, flagp);
}

// Round 9
// 302.860 us; speedup vs baseline: 1.1850x; 1.0374x over previous
//
#include <hip/hip_runtime.h>
#include <hip/hip_bf16.h>

typedef __hip_bfloat16 bf16;
typedef __attribute__((ext_vector_type(8))) short bf8_t;  // 8 bf16 (4 VGPR)
typedef __attribute__((ext_vector_type(4))) float f4_t;

__device__ __forceinline__ float b2f(bf16 x) { return __bfloat162float(x); }

__device__ __forceinline__ float ldany(const void* p, size_t i, int isbf) {
    return isbf ? b2f(((const bf16*)p)[i]) : ((const float*)p)[i];
}

// fp32 -> bf16 (RTN-even), bit pattern as short
__device__ __forceinline__ short f2b(float f) {
    unsigned u = __builtin_bit_cast(unsigned, f);
    u += 0x7fffu + ((u >> 16) & 1u);
    return (short)(u >> 16);
}

__device__ __forceinline__ void gload16(const short* g, short* l) {
    __builtin_amdgcn_global_load_lds(
        (const __attribute__((address_space(1))) void*)g,
        (__attribute__((address_space(3))) void*)l, 16, 0, 0);
}

__device__ __forceinline__ void fma4(float4& a, const float4& x,
                                     const float4& y) {
    a.x += x.x * y.x; a.y += x.y * y.y;
    a.z += x.z * y.z; a.w += x.w * y.w;
}
__device__ __forceinline__ void fma4s(float4& a, const float4& x, float s) {
    a.x += x.x * s; a.y += x.y * s; a.z += x.z * s; a.w += x.w * s;
}
__device__ __forceinline__ float sum4(const float4& a) {
    return (a.x + a.y) + (a.z + a.w);
}
// component select; folds to static with unrolled constant c
__device__ __forceinline__ float getc(const float4& v, int c) {
    return c == 0 ? v.x : c == 1 ? v.y : c == 2 ? v.z : v.w;
}

// ---------------------------------------------------------------- prep
// detect (per-block local) + to-bf16 (vectorized) + weight transpose
// (R9: float4/short4 both sides of the transpose).
struct WT15 {
    const void* src[15];
};

__global__ __launch_bounds__(256) void k_prep(
    const void* __restrict__ dec, const void* __restrict__ enc,
    const void* __restrict__ p, short* __restrict__ dec_bf,
    short* __restrict__ enc_bf, short* __restrict__ p_bf, WT15 w,
    short* __restrict__ wt, short* __restrict__ ff1t,
    short* __restrict__ ff2t, int* __restrict__ flagp) {
    __shared__ float T[32][33];
    __shared__ int cntS;
    if (threadIdx.x == 0) cntS = 0;
    __syncthreads();
    {
        float f = b2f(((const bf16*)dec)[threadIdx.x]);  // first 256 bf16
        float a = fabsf(f);
        int bad = (!(a < 1e10f) || (a != 0.f && a < 1e-20f)) ? 1 : 0;
#pragma unroll
        for (int off = 32; off >= 1; off >>= 1)
            bad += __shfl_xor(bad, off, 64);
        if ((threadIdx.x & 63) == 0) atomicAdd(&cntS, bad);
    }
    __syncthreads();
    int isbf = (cntS >= 3) ? 0 : 1;
    if (blockIdx.x == 0 && threadIdx.x == 0) *flagp = isbf;
    int id = blockIdx.x;
    if (id < 2080) {  // to-bf16: 2129920 elements, 4/thread vectorized
        size_t i4 = ((size_t)id * 256 + threadIdx.x) * 4;
        const void* src;
        short* dst;
        size_t idx;
        if (i4 < 1048576) { src = dec; dst = dec_bf; idx = i4; }
        else if (i4 < 2097152) { src = enc; dst = enc_bf; idx = i4 - 1048576; }
        else { src = p; dst = p_bf; idx = i4 - 2097152; }
        if (isbf) {
            *(short4*)&dst[idx] =
                ((const short4*)((const short*)src))[idx >> 2];
        } else {
            float4 f = ((const float4*)((const float*)src))[idx >> 2];
            short4 o;
            o.x = f2b(f.x); o.y = f2b(f.y); o.z = f2b(f.z); o.w = f2b(f.w);
            *(short4*)&dst[idx] = o;
        }
        return;
    }
    id -= 2080;
    const void* src;
    short* d;
    int K, N, bx, by;
    if (id < 3328) {              // 13 square 512x512 slabs
        int slab = id >> 8, rem = id & 255;
        src = w.src[slab];
        d = wt + (size_t)slab * 262144;
        K = 512; N = 512;
        bx = rem & 15; by = rem >> 4;
    } else if (id < 4352) {       // ff1
        int rem = id - 3328;
        src = w.src[13]; d = ff1t;
        K = 512; N = 2048;
        bx = rem & 63; by = rem >> 6;
    } else {                      // ff2
        int rem = id - 4352;
        src = w.src[14]; d = ff2t;
        K = 2048; N = 512;
        bx = rem & 15; by = rem >> 4;
    }
    int nb = bx * 32, kb = by * 32;
    int rr = threadIdx.x >> 3;        // 0..31
    int c4 = (threadIdx.x & 7) * 4;   // 0,4,..,28
    if (isbf) {
        short4 s4 = *(const short4*)((const short*)src +
                                     (size_t)(kb + rr) * N + nb + c4);
        T[rr][c4 + 0] = b2f(*(bf16*)&s4.x);
        T[rr][c4 + 1] = b2f(*(bf16*)&s4.y);
        T[rr][c4 + 2] = b2f(*(bf16*)&s4.z);
        T[rr][c4 + 3] = b2f(*(bf16*)&s4.w);
    } else {
        float4 f4 = *(const float4*)((const float*)src +
                                     (size_t)(kb + rr) * N + nb + c4);
        T[rr][c4 + 0] = f4.x; T[rr][c4 + 1] = f4.y;
        T[rr][c4 + 2] = f4.z; T[rr][c4 + 3] = f4.w;
    }
    __syncthreads();
    short4 o;
    o.x = f2b(T[c4 + 0][rr]);
    o.y = f2b(T[c4 + 1][rr]);
    o.z = f2b(T[c4 + 2][rr]);
    o.w = f2b(T[c4 + 3][rr]);
    *(short4*)&d[(size_t)(nb + rr) * K + kb + c4] = o;
}

// ---------------------------------------------------------------- MFMA GEMM
// R4 structure (best measured): 2-buffer LDS, global_load_lds(16B),
// STAGE(next) -> MFMA(cur) -> vmcnt(0) -> barrier.
struct GJob {
    const short* A;
    const short* W[4];
    const void* Bias[4];
    float scale[4];
    float* Out[4];
    short* OutBf[4];
    const float* Res;
    const void* ResAny;
    int Nper, K, relu;
    int gx, nblk, blk0;
};
struct GTail {
    int blk0;
    const float* partC;
    const float* ml;
    const void* p_in;
    const void* gv;
    const void* bv;
    short* yp_bf;
    void* outany;
    unsigned long long ooff;
};
struct GJobs {
    GJob j[3];
    GTail tail;
    int nj;
};

__device__ void red_ln_dev(const GTail& T, int row, int isbf, float* red) {
    int b = row >> 5, i = row & 31;
    float v[2];
#pragma unroll
    for (int t = 0; t < 2; t++) {
        int col = (int)threadIdx.x + t * 256;
        int h = col >> 6, dd = col & 63;
        int bh = b * 8 + h;
        float M = -1e30f;
        for (int ks2 = 0; ks2 < 16; ks2++)
            M = fmaxf(M, T.ml[((size_t)bh * 16 + ks2) * 64 + i * 2]);
        float L = 0.f, acc = 0.f;
        for (int ks2 = 0; ks2 < 16; ks2++) {
            float m = T.ml[((size_t)bh * 16 + ks2) * 64 + i * 2];
            float l = T.ml[((size_t)bh * 16 + ks2) * 64 + i * 2 + 1];
            float w = expf(m - M);
            L += l * w;
            acc += T.partC[((size_t)bh * 16 + ks2) * 2048 + i * 64 + dd] * w;
        }
        float raw = acc / L;
        size_t o = (size_t)(b * 32 + i) * 512 + col;
        T.yp_bf[o] = f2b(raw);
        v[t] = raw + ldany(T.p_in, o, isbf);
    }
    int wave = threadIdx.x >> 6, lane = threadIdx.x & 63;
    float sum = v[0] + v[1];
#pragma unroll
    for (int off = 32; off >= 1; off >>= 1) sum += __shfl_xor(sum, off, 64);
    if (lane == 0) red[wave] = sum;
    __syncthreads();
    float mean = (red[0] + red[1] + red[2] + red[3]) * (1.f / 512.f);
    float var = 0.f;
#pragma unroll
    for (int t = 0; t < 2; t++) {
        float dd = v[t] - mean;
        var += dd * dd;
    }
#pragma unroll
    for (int off = 32; off >= 1; off >>= 1) var += __shfl_xor(var, off, 64);
    if (lane == 0) red[wave + 4] = var;
    __syncthreads();
    var = (red[4] + red[5] + red[6] + red[7]) * (1.f / 512.f);
    float inv = rsqrtf(var + 1e-5f);
#pragma unroll
    for (int t = 0; t < 2; t++) {
        int col = (int)threadIdx.x + t * 256;
        size_t o = (size_t)((row >> 5) * 32 + (row & 31)) * 512 + col;
        float y = (v[t] - mean) * inv * ldany(T.gv, col, isbf) +
                  ldany(T.bv, col, isbf);
        if (isbf)
            ((bf16*)T.outany + T.ooff)[o] = __float2bfloat16(y);
        else
            ((float*)T.outany + T.ooff)[o] = y;
    }
}

__global__ __launch_bounds__(256, 4) void k_gemm_mfma(
    GJobs gs, const int* __restrict__ flagp) {
    __shared__ __align__(16) short As[2][64 * 64];
    __shared__ __align__(16) short Bs[2][64 * 64];
    __shared__ float redS[8];
    int isbf = *flagp;
    int id = blockIdx.x;
    if (id >= gs.tail.blk0) {
        red_ln_dev(gs.tail, id - gs.tail.blk0, isbf, redS);
        return;
    }
    int tid = threadIdx.x;
    int wave = tid >> 6, lane = tid & 63;
    int quad = lane >> 4, l16 = lane & 15;
    int ji = 0;
    if (gs.nj > 1 && id >= gs.j[1].blk0) ji = 1;
    if (gs.nj > 2 && id >= gs.j[2].blk0) ji = 2;
    const GJob& jb = gs.j[ji];
    int lid = id - jb.blk0;
    int gx = jb.gx, nblk = jb.nblk;
    int bx, by;
    if ((nblk & 7) == 0) {
        int per = nblk >> 3;
        int id2 = (lid & 7) * per + (lid >> 3);
        by = id2 / gx;
        bx = id2 - by * gx;
    } else {
        by = lid / gx;
        bx = lid - by * gx;
    }
    int K = jb.K;
    int mb = by * 64;
    int nbg = bx * 64;
    int slot = nbg / jb.Nper;
    int nb = nbg - slot * jb.Nper;
    const short* Wt = jb.W[slot];
    const short* A = jb.A;
    int wn = wave * 16;
    f4_t acc[4] = {};

    const short* Ap = A + (size_t)mb * K;
    const short* Wp = Wt + (size_t)nb * K;
    int w8 = wave * 8;
    int lr = lane >> 3;
    int lc = ((lane & 7) ^ lr) * 8;  // swizzled short offset within row
    const short* ga0 = Ap + (size_t)(w8 + lr) * K + lc;
    const short* gb0 = Wp + (size_t)(w8 + lr) * K + lc;
    short* la0 = &As[0][w8 * 64];
    short* lb0 = &Bs[0][w8 * 64];

    auto stage = [&](int buf, int k) {
        gload16(ga0 + k, la0 + buf * 4096);
        gload16(ga0 + (size_t)32 * K + k, la0 + buf * 4096 + 32 * 64);
        gload16(gb0 + k, lb0 + buf * 4096);
        gload16(gb0 + (size_t)32 * K + k, lb0 + buf * 4096 + 32 * 64);
    };

    int sw = l16 & 7;

    stage(0, 0);
    asm volatile("s_waitcnt vmcnt(0)" ::: "memory");
    __builtin_amdgcn_s_barrier();
    int cur = 0;
    for (int k0 = 0; k0 < K; k0 += 64) {
        int kn = k0 + 64;
        if (kn < K) stage(cur ^ 1, kn);
#pragma unroll
        for (int half = 0; half < 2; half++) {
            bf8_t b = *(const bf8_t*)&Bs[cur][(wn + l16) * 64 +
                                             ((half * 4 + quad) ^ sw) * 8];
#pragma unroll
            for (int fi = 0; fi < 4; fi++) {
                bf8_t a = *(const bf8_t*)&As[cur][(fi * 16 + l16) * 64 +
                                                  ((half * 4 + quad) ^ sw) * 8];
                acc[fi] = __builtin_amdgcn_mfma_f32_16x16x32_bf16(a, b,
                                                                  acc[fi],
                                                                  0, 0, 0);
            }
        }
        asm volatile("s_waitcnt vmcnt(0)" ::: "memory");
        __builtin_amdgcn_s_barrier();
        cur ^= 1;
    }
    const void* Bias = jb.Bias[slot];
    float scale = jb.scale[slot];
    float* O = jb.Out[slot];
    short* Ob = jb.OutBf[slot];
    const float* Res = jb.Res;
    const void* ResAny = jb.ResAny;
    int Nper = jb.Nper;
    int relu = jb.relu;
    int n = nb + wn + l16;
    float bia = ldany(Bias, n, isbf);
#pragma unroll
    for (int fi = 0; fi < 4; fi++) {
#pragma unroll
        for (int r = 0; r < 4; r++) {
            int m = mb + fi * 16 + quad * 4 + r;
            float v = (acc[fi][r] + bia) * scale;
            if (relu) v = fmaxf(v, 0.f);
            if (Res) v += Res[(size_t)m * Nper + n];
            if (ResAny) v += ldany(ResAny, (size_t)m * Nper + n, isbf);
            if (O) O[(size_t)m * Nper + n] = v;
            if (Ob) Ob[(size_t)m * Nper + n] = f2b(v);
        }
    }
}

// ---------------------------------------------------------------- ECA phase 1
// R9: 512 threads (was 256; 1 block/CU -> serial per-thread work was the
// critical path). Per-output accumulation order unchanged.
__global__ __launch_bounds__(512) void k_eca1_f(
    const float* __restrict__ pcp, const float* __restrict__ pqp,
    const float* __restrict__ kp, const float* __restrict__ vp,
    float* __restrict__ pattn, float* __restrict__ L1,
    float* __restrict__ L2) {
    __shared__ float Ks[64][68];
    __shared__ float Vs[64][68];
    __shared__ float Ps[64][36];
    int bh = blockIdx.y, c = blockIdx.x;
    int b = bh >> 3, h = bh & 7;
    int tid = threadIdx.x;
    size_t rowbase = (size_t)b * 1024 + c * 64;
    // phase 0: pc -> Ks (2 iters), pq -> Vs[0..31] (1 iter)
    for (int ch = tid; ch < 1024; ch += 512) {
        int s = ch >> 4, d4 = (ch & 15) * 4;
        *(float4*)&Ks[s][d4] =
            *(const float4*)&pcp[(rowbase + s) * 512 + h * 64 + d4];
    }
    {
        int e = tid >> 4, d4 = (tid & 15) * 4;
        *(float4*)&Vs[e][d4] =
            *(const float4*)&pqp[(size_t)(b * 32 + e) * 512 + h * 64 + d4];
    }
    __syncthreads();
    {
        int e = tid & 31, t0 = tid >> 5;  // t0 0..15, 4 rows each
        float4 a4v[4] = {};
        for (int d4 = 0; d4 < 64; d4 += 4) {
            float4 v = *(const float4*)&Vs[e][d4];
#pragma unroll
            for (int rr = 0; rr < 4; rr++)
                fma4(a4v[rr], *(const float4*)&Ks[t0 + rr * 16][d4], v);
        }
#pragma unroll
        for (int rr = 0; rr < 4; rr++) {
            int r = t0 + rr * 16;
            float s = sum4(a4v[rr]);
            float v = (s > 0.f) ? (s + log2f(1.f + exp2f(-s)))
                                : log2f(1.f + exp2f(s));
            Ps[r][e] = v;
            pattn[((size_t)bh * 1024 + c * 64 + r) * 32 + e] = v;
        }
    }
    __syncthreads();
    // phase 1: K,V chunk (2 iters)
    for (int ch = tid; ch < 1024; ch += 512) {
        int s = ch >> 4, d4 = (ch & 15) * 4;
        size_t gidx = (rowbase + s) * 512 + h * 64 + d4;
        *(float4*)&Ks[s][d4] = *(const float4*)&kp[gidx];
        *(float4*)&Vs[s][d4] = *(const float4*)&vp[gidx];
    }
    __syncthreads();
    size_t lbase = ((size_t)bh * 16 + c) * 2048;
    {
        int e = tid & 31, dd0 = (tid >> 5) * 4;  // 16 dd-groups x 32 e
        float4 a0 = {};
        for (int s = 0; s < 64; s++)
            fma4s(a0, *(const float4*)&Ks[s][dd0], Ps[s][e]);
        L1[lbase + (dd0 + 0) * 32 + e] = a0.x;
        L1[lbase + (dd0 + 1) * 32 + e] = a0.y;
        L1[lbase + (dd0 + 2) * 32 + e] = a0.z;
        L1[lbase + (dd0 + 3) * 32 + e] = a0.w;
    }
    {
        int dd = tid & 63, e0 = (tid >> 6) * 4;  // 8 e-groups x 64 dd
        float4 a0 = {};
        for (int s = 0; s < 64; s++)
            fma4s(a0, *(const float4*)&Ps[s][e0], Vs[s][dd]);
        L2[lbase + (e0 + 0) * 64 + dd] = a0.x;
        L2[lbase + (e0 + 1) * 64 + dd] = a0.y;
        L2[lbase + (e0 + 2) * 64 + dd] = a0.z;
        L2[lbase + (e0 + 3) * 64 + dd] = a0.w;
    }
}

// ---------------------------------------------------------------- chunk scan
__global__ __launch_bounds__(256) void k_scan(float* __restrict__ L1,
                                              float* __restrict__ L2) {
    int gid = blockIdx.x * 256 + threadIdx.x;  // 32768 = 16 bh * 2048
    int bh = gid >> 11, lin = gid & 2047;
    size_t base = (size_t)bh * 16 * 2048 + lin;
    float run = 0.f;
#pragma unroll
    for (int c = 0; c < 16; c++) {
        float v = L1[base + c * 2048];
        L1[base + c * 2048] = run;
        run += v;
    }
    run = 0.f;
#pragma unroll
    for (int c = 0; c < 16; c++) {
        float v = L2[base + c * 2048];
        L2[base + c * 2048] = run;
        run += v;
    }
}

// ---------------------------------------------------------------- ECA3 + MHA1
// 1D grid of 512, type-interleaved (R8): gid<256 -> eca3, gid>=256 -> mha1.
__global__ __launch_bounds__(512) void k_attn_mid(
    const float* __restrict__ qp, const float* __restrict__ kp,
    const float* __restrict__ vp, const float* __restrict__ pattn,
    const float* __restrict__ L1s, const float* __restrict__ L2s,
    short* __restrict__ attnbf, const float* __restrict__ pkq,
    const float* __restrict__ pkk, const float* __restrict__ pkv,
    float* __restrict__ partC, float* __restrict__ ml) {
    __shared__ __align__(16) float smem[15616];
    int gid = blockIdx.x;
    int tid = threadIdx.x;
    if (gid >= 256) {
        // -------- MHA1 partials (flash, 512 thr) --------
        int gl = gid - 256;
        int bh = gl >> 4, ks = gl & 15;
        int b = bh >> 3, h = bh & 7;
        float (*Qs)[68] = (float(*)[68])smem;                   // 32 rows
        float (*Ks)[68] = (float(*)[68])(smem + 2176);          // 64 rows
        float (*Vs)[68] = (float(*)[68])(smem + 6528);          // 64 rows
        float (*Ps)[68] = (float(*)[68])(smem + 10880);         // 32 rows
        {
            int i = tid >> 4, d4 = (tid & 15) * 4;
            *(float4*)&Qs[i][d4] =
                *(const float4*)&pkq[(size_t)(b * 32 + i) * 512 + h * 64 + d4];
        }
        for (int ch = tid; ch < 1024; ch += 512) {
            int kk = ch >> 4, d4 = (ch & 15) * 4;
            size_t g = ((size_t)b * 1024 + ks * 64 + kk) * 512 + h * 64 + d4;
            *(float4*)&Ks[kk][d4] = *(const float4*)&pkk[g];
            *(float4*)&Vs[kk][d4] = *(const float4*)&pkv[g];
        }
        __syncthreads();
        int k = tid & 63, ig = tid >> 6;  // 8 waves x 4 rows
        float4 sa[4] = {};
        for (int d4 = 0; d4 < 64; d4 += 4) {
            float4 kk4 = *(const float4*)&Ks[k][d4];
#pragma unroll
            for (int j = 0; j < 4; j++) {
                float4 q = *(const float4*)&Qs[ig * 4 + j][d4];
                fma4(sa[j], q, kk4);
            }
        }
#pragma unroll
        for (int j = 0; j < 4; j++) {
            float s = sum4(sa[j]);
            float m = s;
#pragma unroll
            for (int off = 32; off >= 1; off >>= 1)
                m = fmaxf(m, __shfl_xor(m, off, 64));
            float e = expf(s - m);
            float l = e;
#pragma unroll
            for (int off = 32; off >= 1; off >>= 1)
                l += __shfl_xor(l, off, 64);
            Ps[ig * 4 + j][k] = e;
            if (k == 0) {
                int i = ig * 4 + j;
                ml[((size_t)bh * 16 + ks) * 64 + i * 2] = m;
                ml[((size_t)bh * 16 + ks) * 64 + i * 2 + 1] = l;
            }
        }
        __syncthreads();
        int dd = k;
        float a[4] = {};
        for (int kk4 = 0; kk4 < 64; kk4 += 4) {
            float v0 = Vs[kk4][dd], v1 = Vs[kk4 + 1][dd];
            float v2 = Vs[kk4 + 2][dd], v3 = Vs[kk4 + 3][dd];
#pragma unroll
            for (int j = 0; j < 4; j++) {
                float4 pv = *(const float4*)&Ps[ig * 4 + j][kk4];
                a[j] += pv.x * v0 + pv.y * v1 + pv.z * v2 + pv.w * v3;
            }
        }
        size_t base = ((size_t)bh * 16 + ks) * 2048;
#pragma unroll
        for (int j = 0; j < 4; j++)
            partC[base + (ig * 4 + j) * 64 + dd] = a[j];
        return;
    }
    // -------- ECA3 --------
    int bh = gid >> 4, c = gid & 15;
    int b = bh >> 3, h = bh & 7;
    float (*R0)[68] = (float(*)[68])smem;            // 64x68
    float (*R1)[68] = (float(*)[68])(smem + 4352);   // 64x68
    float (*Ps)[36] = (float(*)[36])(smem + 8704);   // 64x36
    float* SS = smem + 11008;                        // 2304
    float (*Pr)[36] = (float(*)[36])(smem + 13312);  // 64x36
    size_t rowbase = (size_t)b * 1024 + c * 64;
    for (int ch = tid; ch < 1024; ch += 512) {
        int t = ch >> 4, d4 = (ch & 15) * 4;
        size_t gidx = (rowbase + t) * 512 + h * 64 + d4;
        *(float4*)&R0[t][d4] = *(const float4*)&qp[gidx];
        *(float4*)&R1[t][d4] = *(const float4*)&kp[gidx];
    }
    {
        int t = tid >> 3, e4 = (tid & 7) * 4;
        *(float4*)&Ps[t][e4] =
            *(const float4*)&pattn[((size_t)bh * 1024 + c * 64 + t) * 32 + e4];
    }
    {
        // pre-scanned S1 (exclusive prefix) straight from global
        float4 s4 =
            *(const float4*)&L1s[((size_t)bh * 16 + c) * 2048 + tid * 4];
        int dd = tid >> 3, e4 = (tid & 7) * 4;
        *(float4*)&SS[dd * 36 + e4] = s4;
    }
    __syncthreads();
    int tx = tid & 15, ty = tid >> 4;
    float4 a1v[2][4] = {};
    float qs1[2][2] = {};
    for (int d4 = 0; d4 < 64; d4 += 4) {
        float4 q0 = *(const float4*)&R0[ty * 2][d4];
        float4 q1 = *(const float4*)&R0[ty * 2 + 1][d4];
#pragma unroll
        for (int j = 0; j < 4; j++) {
            // rows tx+16j: bank-group spreads over all 8 groups
            float4 kk = *(const float4*)&R1[tx + 16 * j][d4];
            fma4(a1v[0][j], q0, kk);
            fma4(a1v[1][j], q1, kk);
        }
#pragma unroll
        for (int cc = 0; cc < 4; cc++) {
            float2 s01 = *(const float2*)&SS[(d4 + cc) * 36 + tx * 2];
            float qa = getc(q0, cc), qb = getc(q1, cc);
            qs1[0][0] += qa * s01.x;
            qs1[0][1] += qa * s01.y;
            qs1[1][0] += qb * s01.x;
            qs1[1][1] += qb * s01.y;
        }
    }
    __syncthreads();
    // A1 writeback + qs1 seed; V load; SS-L2 load (single shot, all 512
    // threads = exactly 512 quads, overlaps the triangular phase).
#pragma unroll
    for (int i = 0; i < 2; i++) {
#pragma unroll
        for (int j = 0; j < 4; j++)
            R0[ty * 2 + i][tx + 16 * j] = sum4(a1v[i][j]);
        Pr[ty * 2 + i][tx * 2] = qs1[i][0];
        Pr[ty * 2 + i][tx * 2 + 1] = qs1[i][1];
    }
    for (int ch = tid; ch < 1024; ch += 512) {
        int t = ch >> 4, d4 = (ch & 15) * 4;
        *(float4*)&R1[t][d4] =
            *(const float4*)&vp[(rowbase + t) * 512 + h * 64 + d4];
    }
    {
        float4 s4 =
            *(const float4*)&L2s[((size_t)bh * 16 + c) * 2048 + tid * 4];
        int e = tid >> 4, d4 = (tid & 15) * 4;
        *(float4*)&SS[e * 68 + d4] = s4;
    }
    __syncthreads();
    {
        // aw = (prefix + lower-tri(A1) . Ps) / count, masked full-unroll
        int e = tid & 31, t0 = (tid >> 5) * 4;
        float sacc[4];
#pragma unroll
        for (int k2 = 0; k2 < 4; k2++) sacc[k2] = Pr[t0 + k2][e];
#pragma unroll
        for (int s2 = 0; s2 < 64; s2++) {
            float p = Ps[s2][e];
#pragma unroll
            for (int k2 = 0; k2 < 4; k2++) {
                float w = R0[t0 + k2][s2];
                sacc[k2] += (s2 <= t0 + k2) ? w * p : 0.f;
            }
        }
#pragma unroll
        for (int k2 = 0; k2 < 4; k2++)
            Pr[t0 + k2][e] = sacc[k2] / (float)(c * 64 + t0 + k2 + 1);
    }
    __syncthreads();
    {
        // wave-parallel softmax: 8 lanes/row x 4 elems
        int row = tid >> 3, sub = tid & 7;
        float4 pv = *(const float4*)&Pr[row][sub * 4];
        float m = fmaxf(fmaxf(pv.x, pv.y), fmaxf(pv.z, pv.w));
#pragma unroll
        for (int off = 4; off >= 1; off >>= 1)
            m = fmaxf(m, __shfl_xor(m, off, 64));
        pv.x = expf(pv.x - m);
        pv.y = expf(pv.y - m);
        pv.z = expf(pv.z - m);
        pv.w = expf(pv.w - m);
        float sum = sum4(pv);
#pragma unroll
        for (int off = 4; off >= 1; off >>= 1)
            sum += __shfl_xor(sum, off, 64);
        float inv = 1.f / sum;
        pv.x *= inv; pv.y *= inv; pv.z *= inv; pv.w *= inv;
        *(float4*)&Pr[row][sub * 4] = pv;
    }
    __syncthreads();
    float a2r[2][4] = {};
    float ps2[2][4] = {};
    for (int e4 = 0; e4 < 32; e4 += 4) {
        float4 pr0 = *(const float4*)&Pr[ty * 2][e4];
        float4 pr1 = *(const float4*)&Pr[ty * 2 + 1][e4];
        float4 bj[4];
        float4 vv[4];
#pragma unroll
        for (int j = 0; j < 4; j++)
            bj[j] = *(const float4*)&Ps[tx + 16 * j][e4];  // remapped rows
#pragma unroll
        for (int cc = 0; cc < 4; cc++)
            vv[cc] = *(const float4*)&SS[(e4 + cc) * 68 + tx * 4];
#pragma unroll
        for (int cc = 0; cc < 4; cc++) {
            float pa = getc(pr0, cc), pb = getc(pr1, cc);
#pragma unroll
            for (int j = 0; j < 4; j++) {
                float bv_ = getc(bj[j], cc);
                float vvv = getc(vv[cc], j);
                a2r[0][j] += pa * bv_;
                a2r[1][j] += pb * bv_;
                ps2[0][j] += pa * vvv;
                ps2[1][j] += pb * vvv;
            }
        }
    }
    __syncthreads();
#pragma unroll
    for (int i = 0; i < 2; i++)
#pragma unroll
        for (int j = 0; j < 4; j++)
            R0[ty * 2 + i][tx + 16 * j] = a2r[i][j];  // remapped s-cols
    __syncthreads();
    {
        // PV: acch = ps2 + lower-tri(A2) . V, masked full-unroll, b128 V rows
        float4 acc4[2];
#pragma unroll
        for (int i = 0; i < 2; i++) {
            acc4[i].x = ps2[i][0]; acc4[i].y = ps2[i][1];
            acc4[i].z = ps2[i][2]; acc4[i].w = ps2[i][3];
        }
        int t0 = ty * 2;
#pragma unroll
        for (int s = 0; s < 64; s++) {
            float4 r = *(const float4*)&R1[s][tx * 4];
#pragma unroll
            for (int i = 0; i < 2; i++) {
                float a2v = R0[t0 + i][s];
                float m = (s <= t0 + i) ? a2v : 0.f;
                fma4s(acc4[i], r, m);
            }
        }
#pragma unroll
        for (int i = 0; i < 2; i++) {
            int t = t0 + i;
            float inv = 1.f / (float)(c * 64 + t + 1);
            short4 o;
            o.x = f2b(acc4[i].x * inv);
            o.y = f2b(acc4[i].y * inv);
            o.z = f2b(acc4[i].z * inv);
            o.w = f2b(acc4[i].w * inv);
            *(short4*)&attnbf[(rowbase + t) * 512 + h * 64 + tx * 4] = o;
        }
    }
}

// ---------------------------------------------------------------- MHA2
// R9: 512 threads (was 256, 1 block/CU). Each thread: 4 scores (8-lane
// shfl-reduce softmax) + 8 PV dds.
__global__ __launch_bounds__(512) void k_mha2(const float* __restrict__ upq,
                                              const float* __restrict__ upk,
                                              const float* __restrict__ upv,
                                              short* __restrict__ yxbf) {
    __shared__ float Ksm[32][68];
    __shared__ float Vsm[32][68];
    __shared__ float Qsm[64][68];
    __shared__ float Prm[64][36];
    int bh = blockIdx.y, c = blockIdx.x;
    int b = bh >> 3, h = bh & 7;
    int tid = threadIdx.x;
    {
        int e = tid >> 4, d4 = (tid & 15) * 4;  // 32x16 = 512
        size_t g = (size_t)(b * 32 + e) * 512 + h * 64 + d4;
        *(float4*)&Ksm[e][d4] = *(const float4*)&upk[g];
        *(float4*)&Vsm[e][d4] = *(const float4*)&upv[g];
    }
    for (int ch = tid; ch < 1024; ch += 512) {
        int t = ch >> 4, d4 = (ch & 15) * 4;
        *(float4*)&Qsm[t][d4] =
            *(const float4*)&upq[((size_t)b * 1024 + c * 64 + t) * 512 +
                                 h * 64 + d4];
    }
    __syncthreads();
    int row = tid >> 3, r = tid & 7;  // 64 rows x 8 lanes
    float4 sj[4] = {};
    for (int d4 = 0; d4 < 64; d4 += 4) {
        float4 q = *(const float4*)&Qsm[row][d4];
#pragma unroll
        for (int j = 0; j < 4; j++) {
            float4 kk = *(const float4*)&Ksm[r * 4 + j][d4];
            fma4(sj[j], q, kk);
        }
    }
    float p[4];
#pragma unroll
    for (int j = 0; j < 4; j++) p[j] = sum4(sj[j]);
    float m = fmaxf(fmaxf(p[0], p[1]), fmaxf(p[2], p[3]));
#pragma unroll
    for (int off = 4; off >= 1; off >>= 1)
        m = fmaxf(m, __shfl_xor(m, off, 64));
    float sum = 0.f;
#pragma unroll
    for (int j = 0; j < 4; j++) {
        p[j] = expf(p[j] - m);
        sum += p[j];
    }
#pragma unroll
    for (int off = 4; off >= 1; off >>= 1)
        sum += __shfl_xor(sum, off, 64);
    float inv = 1.f / sum;
#pragma unroll
    for (int j = 0; j < 4; j++) Prm[row][r * 4 + j] = p[j] * inv;
    __syncthreads();
    float4 a0 = {}, a1 = {};
    int dd0 = r * 8;
    for (int e = 0; e < 32; e++) {
        float pe = Prm[row][e];
        fma4s(a0, *(const float4*)&Vsm[e][dd0], pe);
        fma4s(a1, *(const float4*)&Vsm[e][dd0 + 4], pe);
    }
    size_t obase = ((size_t)b * 1024 + c * 64 + row) * 512 + h * 64 + dd0;
    short4 o0, o1;
    o0.x = f2b(a0.x); o0.y = f2b(a0.y); o0.z = f2b(a0.z); o0.w = f2b(a0.w);
    o1.x = f2b(a1.x); o1.y = f2b(a1.y); o1.z = f2b(a1.z); o1.w = f2b(a1.w);
    *(short4*)&yxbf[obase] = o0;
    *(short4*)&yxbf[obase + 4] = o1;
}

// ---------------------------------------------------------------- LayerNorm
__global__ __launch_bounds__(256) void k_ln(
    const float* __restrict__ x, const float* __restrict__ residf,
    const void* __restrict__ residany, const void* __restrict__ gv,
    const void* __restrict__ bv, float* __restrict__ out32,
    short* __restrict__ dupbf, void* __restrict__ outany, size_t ooff,
    const int* __restrict__ flagp) {
    int isbf = *flagp;
    int wave = threadIdx.x >> 6, lane = threadIdx.x & 63;
    int row = blockIdx.x * 4 + wave;
    const float* px = x + (size_t)row * 512;
    float v[8];
#pragma unroll
    for (int j = 0; j < 8; j++) {
        int col = lane + 64 * j;
        v[j] = px[col];
        if (residf) v[j] += residf[(size_t)row * 512 + col];
        if (residany) v[j] += ldany(residany, (size_t)row * 512 + col, isbf);
    }
    float sum = 0.f;
#pragma unroll
    for (int j = 0; j < 8; j++) sum += v[j];
#pragma unroll
    for (int off = 32; off >= 1; off >>= 1) sum += __shfl_xor(sum, off, 64);
    float mean = sum * (1.f / 512.f);
    float var = 0.f;
#pragma unroll
    for (int j = 0; j < 8; j++) {
        float d = v[j] - mean;
        var += d * d;
    }
#pragma unroll
    for (int off = 32; off >= 1; off >>= 1) var += __shfl_xor(var, off, 64);
    var *= (1.f / 512.f);
    float inv = rsqrtf(var + 1e-5f);
#pragma unroll
    for (int j = 0; j < 8; j++) {
        int col = lane + 64 * j;
        float y = (v[j] - mean) * inv * ldany(gv, col, isbf) +
                  ldany(bv, col, isbf);
        size_t oidx = (size_t)row * 512 + col;
        if (out32) out32[oidx] = y;
        if (dupbf) dupbf[oidx] = f2b(y);
        if (outany) {
            if (isbf)
                ((bf16*)outany + ooff)[oidx] = __float2bfloat16(y);
            else
                ((float*)outany + ooff)[oidx] = y;
        }
    }
}

// ================================================================ launch
extern "C" void kernel_launch(void* const* d_in, const int* in_sizes, int n_in,
                              void* d_out, int out_size, void* d_ws,
                              size_t ws_size, hipStream_t stream) {
    (void)in_sizes; (void)n_in; (void)out_size; (void)ws_size;
    const void* dec_in = d_in[0];
    const void* p_in = d_in[1];
    const void* enc_in = d_in[2];

    const size_t M1 = 1048576;
    float* ws = (float*)d_ws;
    float* A_ = ws + 0 * M1;  // sa_q (eca3 q) -> yx2 fp32
    float* B_ = ws + 1 * M1;  // sa_k ; later ff1_bf zone
    float* C_ = ws + 2 * M1;  // sa_v -> up_q
    float* D_ = ws + 3 * M1;  // sa_pc -> mha1 partC -> ca_lin out
    float* E_ = ws + 4 * M1;  // bf16 zone: attn_bf / mha2_bf
    float* F_ = ws + 5 * M1;  // sa_out+resid -> ff2 out
    float* S_ = ws + 6 * M1;  // scratch
    float* pattn = S_;                  // 512K floats
    float* L1 = S_ + 524288;            // 512K
    float* L2 = S_ + 1048576;           // 512K
    float* pqp = S_ + 1572864;          // 32K
    float* pkq = S_ + 1605632;          // 32K
    float* ml = S_ + 1638400;           // 16K
    float* upk = S_ + 1671168;          // 32K
    float* upv = S_ + 1703936;          // 32K
    float* partC = D_;                  // D_ dead between eca1 and ca_lin
    int* flagp = (int*)(S_ + 1736704);
    float* PKK = ws + 14 * M1;          // pk_k proj (fp32, 1M)
    float* PKV = ws + 15 * M1;          // pk_v proj (fp32, 1M)
    // bf16 buffers (shorts)
    short* attn_bf = (short*)E_;
    short* mha2_bf = (short*)(E_ + 524288);
    short* ff1_bf = (short*)B_;                       // spans B_..C_
    short* dec_bf = (short*)(ws + 7 * M1 + 786432);
    short* enc_bf = dec_bf + M1;
    short* p_bf = enc_bf + M1;
    short* F_bf = p_bf + 32768;
    short* yp_bf = F_bf + M1;
    short* yx2_bf = yp_bf + 32768;
    short* wt = yx2_bf + M1;
    short* ff1t = wt + 13 * 262144;
    short* ff2t = ff1t + M1;
    auto WTp = [&](int wi) { return wt + (size_t)((wi - 6) / 2) * 262144; };
    auto Bv = [&](int i) { return (const void*)d_in[i]; };
    short* nb16 = nullptr;
    float* nf32 = nullptr;
    const int BIG = 0x7fffffff;

    hipStream_t S = stream;
    // 1. prep: detect + tobf (vectorized) + wtrans (vectorized)
    {
        WT15 w;
        for (int s = 0; s < 13; s++) w.src[s] = d_in[6 + 2 * s];
        w.src[13] = d_in[38];
        w.src[14] = d_in[40];
        k_prep<<<7456, 256, 0, S>>>(dec_in, enc_in, p_in, dec_bf, enc_bf,
                                    p_bf, w, wt, ff1t, ff2t, flagp);
    }

    // 2. G1: sa projections + p projections + pk_k/pk_v
    {
        GJobs g{};
        g.nj = 3;
        g.tail.blk0 = BIG;
        GJob& a = g.j[0];
        a.A = dec_bf;
        a.W[0] = WTp(6); a.W[1] = WTp(10); a.W[2] = WTp(12); a.W[3] = WTp(14);
        a.Bias[0] = Bv(7); a.Bias[1] = Bv(11); a.Bias[2] = Bv(13);
        a.Bias[3] = Bv(15);
        a.scale[0] = 0.125f; a.scale[1] = 1.f; a.scale[2] = 1.f;
        a.scale[3] = 1.f;
        a.Out[0] = A_; a.Out[1] = D_; a.Out[2] = B_; a.Out[3] = C_;
        a.OutBf[0] = nb16; a.OutBf[1] = nb16; a.OutBf[2] = nb16;
        a.OutBf[3] = nb16;
        a.Res = nullptr; a.ResAny = nullptr;
        a.Nper = 512; a.K = 512; a.relu = 0;
        a.gx = 32; a.nblk = 1024; a.blk0 = 0;
        GJob& b = g.j[1];
        b.A = p_bf;
        b.W[0] = WTp(8); b.W[1] = WTp(18); b.W[2] = WTp(8); b.W[3] = WTp(8);
        b.Bias[0] = Bv(9); b.Bias[1] = Bv(19); b.Bias[2] = Bv(9);
        b.Bias[3] = Bv(9);
        b.scale[0] = 0.125f; b.scale[1] = 0.125f; b.scale[2] = 0.f;
        b.scale[3] = 0.f;
        b.Out[0] = pqp; b.Out[1] = pkq; b.Out[2] = pqp; b.Out[3] = pqp;
        b.OutBf[0] = nb16; b.OutBf[1] = nb16; b.OutBf[2] = nb16;
        b.OutBf[3] = nb16;
        b.Res = nullptr; b.ResAny = nullptr;
        b.Nper = 512; b.K = 512; b.relu = 0;
        b.gx = 16; b.nblk = 16; b.blk0 = 1024;
        GJob& cj = g.j[2];
        cj.A = enc_bf;
        cj.W[0] = WTp(20); cj.W[1] = WTp(22); cj.W[2] = WTp(20);
        cj.W[3] = WTp(20);
        cj.Bias[0] = Bv(21); cj.Bias[1] = Bv(23); cj.Bias[2] = Bv(21);
        cj.Bias[3] = Bv(21);
        cj.scale[0] = 1.f; cj.scale[1] = 1.f; cj.scale[2] = 1.f;
        cj.scale[3] = 1.f;
        cj.Out[0] = PKK; cj.Out[1] = PKV; cj.Out[2] = PKK; cj.Out[3] = PKK;
        cj.OutBf[0] = nb16; cj.OutBf[1] = nb16; cj.OutBf[2] = nb16;
        cj.OutBf[3] = nb16;
        cj.Res = nullptr; cj.ResAny = nullptr;
        cj.Nper = 512; cj.K = 512; cj.relu = 0;
        cj.gx = 16; cj.nblk = 512; cj.blk0 = 1040;
        k_gemm_mfma<<<1552, 256, 0, S>>>(g, flagp);
    }
    // 3. eca1 (pattn fused, 512 thr)
    k_eca1_f<<<dim3(16, 16), 512, 0, S>>>(D_, pqp, B_, C_, pattn, L1, L2);
    // 3b. chunk scan (exclusive prefix)
    k_scan<<<128, 256, 0, S>>>(L1, L2);
    // 4. eca3 + mha1 partials (1D grid, type-interleaved pairing)
    k_attn_mid<<<512, 512, 0, S>>>(A_, B_, C_, pattn, L1, L2, attn_bf, pkq,
                                   PKK, PKV, partC, ml);
    // 5. G2: sa_out (+dec residual) + tail: mha1 reduce + Yp LN
    {
        GJobs g{};
        g.nj = 1;
        GJob& a = g.j[0];
        a.A = attn_bf;
        a.W[0] = WTp(16); a.W[1] = WTp(16); a.W[2] = WTp(16); a.W[3] = WTp(16);
        a.Bias[0] = Bv(17); a.Bias[1] = Bv(17); a.Bias[2] = Bv(17);
        a.Bias[3] = Bv(17);
        a.scale[0] = 1.f; a.scale[1] = 1.f; a.scale[2] = 1.f; a.scale[3] = 1.f;
        a.Out[0] = F_; a.Out[1] = F_; a.Out[2] = F_; a.Out[3] = F_;
        a.OutBf[0] = F_bf; a.OutBf[1] = F_bf; a.OutBf[2] = F_bf;
        a.OutBf[3] = F_bf;
        a.Res = nullptr; a.ResAny = dec_in;
        a.Nper = 512; a.K = 512; a.relu = 0;
        a.gx = 8; a.nblk = 256; a.blk0 = 0;
        g.tail.blk0 = 256;
        g.tail.partC = partC;
        g.tail.ml = ml;
        g.tail.p_in = p_in;
        g.tail.gv = d_in[32];
        g.tail.bv = d_in[33];
        g.tail.yp_bf = yp_bf;
        g.tail.outany = d_out;
        g.tail.ooff = 1048576ull;
        k_gemm_mfma<<<320, 256, 0, S>>>(g, flagp);
    }
    // 6. G3: up_k/up_v + up_q
    {
        GJobs g{};
        g.nj = 2;
        g.tail.blk0 = BIG;
        GJob& a = g.j[0];
        a.A = yp_bf;
        a.W[0] = WTp(26); a.W[1] = WTp(28); a.W[2] = WTp(26); a.W[3] = WTp(26);
        a.Bias[0] = Bv(27); a.Bias[1] = Bv(29); a.Bias[2] = Bv(27);
        a.Bias[3] = Bv(27);
        a.scale[0] = 1.f; a.scale[1] = 1.f; a.scale[2] = 1.f; a.scale[3] = 1.f;
        a.Out[0] = upk; a.Out[1] = upv; a.Out[2] = upk; a.Out[3] = upk;
        a.OutBf[0] = nb16; a.OutBf[1] = nb16; a.OutBf[2] = nb16;
        a.OutBf[3] = nb16;
        a.Res = nullptr; a.ResAny = nullptr;
        a.Nper = 512; a.K = 512; a.relu = 0;
        a.gx = 16; a.nblk = 16; a.blk0 = 0;
        GJob& b = g.j[1];
        b.A = F_bf;
        b.W[0] = WTp(24); b.W[1] = WTp(24); b.W[2] = WTp(24); b.W[3] = WTp(24);
        b.Bias[0] = Bv(25); b.Bias[1] = Bv(25); b.Bias[2] = Bv(25);
        b.Bias[3] = Bv(25);
        b.scale[0] = 0.125f; b.scale[1] = 0.125f; b.scale[2] = 0.125f;
        b.scale[3] = 0.125f;
        b.Out[0] = C_; b.Out[1] = C_; b.Out[2] = C_; b.Out[3] = C_;
        b.OutBf[0] = nb16; b.OutBf[1] = nb16; b.OutBf[2] = nb16;
        b.OutBf[3] = nb16;
        b.Res = nullptr; b.ResAny = nullptr;
        b.Nper = 512; b.K = 512; b.relu = 0;
        b.gx = 8; b.nblk = 256; b.blk0 = 16;
        k_gemm_mfma<<<272, 256, 0, S>>>(g, flagp);
    }
    // 7. mha2 (512 thr)
    k_mha2<<<dim3(16, 16), 512, 0, S>>>(C_, upk, upv, mha2_bf);
    // 8. G4: ca_lin
    {
        GJobs g{};
        g.nj = 1;
        g.tail.blk0 = BIG;
        GJob& a = g.j[0];
        a.A = mha2_bf;
        a.W[0] = WTp(30); a.W[1] = WTp(30); a.W[2] = WTp(30); a.W[3] = WTp(30);
        a.Bias[0] = Bv(31); a.Bias[1] = Bv(31); a.Bias[2] = Bv(31);
        a.Bias[3] = Bv(31);
        a.scale[0] = 1.f; a.scale[1] = 1.f; a.scale[2] = 1.f; a.scale[3] = 1.f;
        a.Out[0] = D_; a.Out[1] = D_; a.Out[2] = D_; a.Out[3] = D_;
        a.OutBf[0] = nb16; a.OutBf[1] = nb16; a.OutBf[2] = nb16;
        a.OutBf[3] = nb16;
        a.Res = nullptr; a.ResAny = nullptr;
        a.Nper = 512; a.K = 512; a.relu = 0;
        a.gx = 8; a.nblk = 256; a.blk0 = 0;
        k_gemm_mfma<<<256, 256, 0, S>>>(g, flagp);
    }
    // 9. LN -> yx2
    k_ln<<<2048 / 4, 256, 0, S>>>(D_, F_, nullptr, d_in[34], d_in[35], A_,
                                  yx2_bf, nullptr, 0, flagp);
    // 10. G5: ff1 + relu
    {
        GJobs g{};
        g.nj = 1;
        g.tail.blk0 = BIG;
        GJob& a = g.j[0];
        a.A = yx2_bf;
        a.W[0] = ff1t; a.W[1] = ff1t; a.W[2] = ff1t; a.W[3] = ff1t;
        a.Bias[0] = Bv(39); a.Bias[1] = Bv(39); a.Bias[2] = Bv(39);
        a.Bias[3] = Bv(39);
        a.scale[0] = 1.f; a.scale[1] = 1.f; a.scale[2] = 1.f; a.scale[3] = 1.f;
        a.Out[0] = nf32; a.Out[1] = nf32; a.Out[2] = nf32; a.Out[3] = nf32;
        a.OutBf[0] = ff1_bf; a.OutBf[1] = ff1_bf; a.OutBf[2] = ff1_bf;
        a.OutBf[3] = ff1_bf;
        a.Res = nullptr; a.ResAny = nullptr;
        a.Nper = 2048; a.K = 512; a.relu = 1;
        a.gx = 32; a.nblk = 1024; a.blk0 = 0;
        k_gemm_mfma<<<1024, 256, 0, S>>>(g, flagp);
    }
    // 11. G6: ff2
    {
        GJobs g{};
        g.nj = 1;
        g.tail.blk0 = BIG;
        GJob& a = g.j[0];
        a.A = ff1_bf;
        a.W[0] = ff2t; a.W[1] = ff2t; a.W[2] = ff2t; a.W[3] = ff2t;
        a.Bias[0] = Bv(41); a.Bias[1] = Bv(41); a.Bias[2] = Bv(41);
        a.Bias[3] = Bv(41);
        a.scale[0] = 1.f; a.scale[1] = 1.f; a.scale[2] = 1.f; a.scale[3] = 1.f;
        a.Out[0] = F_; a.Out[1] = F_; a.Out[2] = F_; a.Out[3] = F_;
        a.OutBf[0] = nb16; a.OutBf[1] = nb16; a.OutBf[2] = nb16;
        a.OutBf[3] = nb16;
        a.Res = nullptr; a.ResAny = nullptr;
        a.Nper = 512; a.K = 2048; a.relu = 0;
        a.gx = 8; a.nblk = 256; a.blk0 = 0;
        k_gemm_mfma<<<256, 256, 0, S>>>(g, flagp);
    }
    // 12. final LN
    k_ln<<<2048 / 4, 256, 0, S>>>(F_, A_, nullptr, d_in[36], d_in[37],
                                  nullptr, nullptr, d_out, 0, flagp);
}